// Round 11
// baseline (291.441 us; speedup 1.0000x reference)
//
#include <hip/hip_runtime.h>
#include <hip/hip_bf16.h>

// GravNet: 32 graphs x 256 nodes, IN=64, HID=256, OUT=32, K=20, SPACE=3, PROP=2
// SINGLE-KERNEL pipeline (512 blocks x 256 thr, 2 blocks/CU co-resident), 4 in-kernel
// device-wide barriers. vs R9 (493us, passed): barrier fences reduced from per-thread
// __threadfence_system (cache-wide wbl2/inv x every wave = ~120us/barrier) to ONE
// agent-scope __threadfence per block (fences are cache-wide; block shares one CU/L1,
// one XCD/L2 -> tid0's fence covers the whole block). Atomics agent-scope.
//  A: in-block sh1 + knn1 (ILP-4) | weight split | bias-init | X split   -> bar
//  B: gemm1 64x64-tile MFMA split-bf16 + fused s2/h2 partials            -> bar
//  C: knn2 (LDS-staged, ILP-4)                                           -> bar
//  D: gemm2 (K=256) + compact h2c rows + fused s3/h3 partials            -> bar
//  E: knn3 (32 blocks) + final 258->32 matvec
// GEMM x-part: split-bf16 MFMA (hi/lo, 3 products) == fp32 precision, operands pre-split.

#define NGRAPH 32
#define GN 256
#define NTOT (NGRAPH*GN) // 8192
#define KNN 20
#define NBLK 512
#define CTS 65           // CT leading dim (floats)

typedef __attribute__((ext_vector_type(8))) short bf16x8;
typedef __attribute__((ext_vector_type(4))) float f32x4;

__device__ __forceinline__ ushort f2bf(float x) {
    union { float f; unsigned u; } a; a.f = x;
    unsigned r = a.u + 0x7FFFu + ((a.u >> 16) & 1u);   // RNE
    return (ushort)(r >> 16);
}
__device__ __forceinline__ float bf2f(ushort h) {
    union { unsigned u; float f; } b; b.u = ((unsigned)h) << 16;
    return b.f;
}
__device__ __forceinline__ bf16x8 ld8(const ushort* p) {
    return *reinterpret_cast<const bf16x8*>(p);
}
__device__ __forceinline__ unsigned pack2(ushort a, ushort b) {
    return (unsigned)a | ((unsigned)b << 16);
}

// ---- DPP primitives (VALU-only) ----
#define DPP_MIN(v, ctrl, rmask) { \
    unsigned _t = (unsigned)__builtin_amdgcn_update_dpp((int)(v), (int)(v), ctrl, rmask, 0xf, false); \
    (v) = _t < (v) ? _t : (v); }
#define DPP_ADD(v, ctrl, rmask) { \
    float _t = __int_as_float(__builtin_amdgcn_update_dpp(0, __float_as_int(v), ctrl, rmask, 0xf, true)); \
    (v) += _t; }
__device__ __forceinline__ unsigned wave_min_u32(unsigned v) {
    DPP_MIN(v, 0x111, 0xf)
    DPP_MIN(v, 0x112, 0xf)
    DPP_MIN(v, 0x114, 0xf)
    DPP_MIN(v, 0x118, 0xf)
    DPP_MIN(v, 0x142, 0xa)
    DPP_MIN(v, 0x143, 0xc)
    return (unsigned)__builtin_amdgcn_readlane((int)v, 63);
}
__device__ __forceinline__ float wave_sum_f32(float v) {
    DPP_ADD(v, 0x111, 0xf)
    DPP_ADD(v, 0x112, 0xf)
    DPP_ADD(v, 0x114, 0xf)
    DPP_ADD(v, 0x118, 0xf)
    DPP_ADD(v, 0x142, 0xa)
    DPP_ADD(v, 0x143, 0xc)
    return __int_as_float(__builtin_amdgcn_readlane(__float_as_int(v), 63));
}

// ---- serial kNN extraction (phase E only; no early exit) ----
__device__ __forceinline__ void knn_extract(
    unsigned ua, unsigned ub, unsigned uc, unsigned ud,
    float2 hA, float2 hB, float2 hC, float2 hD,
    int lane, float& out0, float& out1)
{
    float acc0 = 0.f, acc1 = 0.f;
#pragma unroll 1
    for (int it = 0; it < KNN; ++it) {
        unsigned m1 = ua < ub ? ua : ub;
        unsigned m2 = uc < ud ? uc : ud;
        unsigned bv = m1 < m2 ? m1 : m2;
        unsigned gv = wave_min_u32(bv);
        float d2 = __uint_as_float(gv);
        float w = __expf(-10.0f * d2);
        unsigned long long mask = __ballot(bv == gv);
        int wl = __ffsll(mask) - 1;
        if (lane == wl) {
            float h0, h1;
            if (ua == gv)      { h0 = hA.x; h1 = hA.y; ua = 0xFFFFFFFFu; }
            else if (ub == gv) { h0 = hB.x; h1 = hB.y; ub = 0xFFFFFFFFu; }
            else if (uc == gv) { h0 = hC.x; h1 = hC.y; uc = 0xFFFFFFFFu; }
            else               { h0 = hD.x; h1 = hD.y; ud = 0xFFFFFFFFu; }
            acc0 = fmaf(w, h0, acc0);
            acc1 = fmaf(w, h1, acc1);
        }
    }
    out0 = wave_sum_f32(acc0);
    out1 = wave_sum_f32(acc1);
}

// ---- 4 kNN rows per wave, chains INTERLEAVED for ILP; sh5 = [256 nodes][5] in LDS ----
__device__ __forceinline__ void knn_rows4(
    const float* sh5, int rbase, int lane, int growbase, float* __restrict__ agg)
{
    float sjx[4], sjy[4], sjz[4], s2j[4];
    float2 hs[4];
#pragma unroll
    for (int t = 0; t < 4; ++t) {
        int j = lane + 64 * t;
        float x = sh5[j * 5 + 0], y = sh5[j * 5 + 1], z = sh5[j * 5 + 2];
        sjx[t] = x; sjy[t] = y; sjz[t] = z;
        s2j[t] = x * x + y * y + z * z;
        hs[t] = make_float2(sh5[j * 5 + 3], sh5[j * 5 + 4]);
    }
    unsigned key[4][4];
    float acc0[4], acc1[4];
#pragma unroll
    for (int r = 0; r < 4; ++r) {
        int rl = rbase + r;
        float s0 = sh5[rl * 5 + 0], s1v = sh5[rl * 5 + 1], s2v = sh5[rl * 5 + 2];
        float s2row = s0 * s0 + s1v * s1v + s2v * s2v;
#pragma unroll
        for (int t = 0; t < 4; ++t) {
            float dot = s0 * sjx[t] + s1v * sjy[t] + s2v * sjz[t];
            float d2 = s2row + s2j[t] - 2.0f * dot;
            key[r][t] = __float_as_uint(d2 > 0.f ? d2 : 0.f);
        }
        acc0[r] = 0.f; acc1[r] = 0.f;
    }
#pragma unroll 1
    for (int it = 0; it < KNN; ++it) {
        unsigned bv[4], gv[4];
#pragma unroll
        for (int r = 0; r < 4; ++r) {
            unsigned m1 = key[r][0] < key[r][1] ? key[r][0] : key[r][1];
            unsigned m2 = key[r][2] < key[r][3] ? key[r][2] : key[r][3];
            bv[r] = m1 < m2 ? m1 : m2;
            gv[r] = bv[r];
        }
#define KSTAGE(ctrl, rmask) { \
        DPP_MIN(gv[0], ctrl, rmask) DPP_MIN(gv[1], ctrl, rmask) \
        DPP_MIN(gv[2], ctrl, rmask) DPP_MIN(gv[3], ctrl, rmask) }
        KSTAGE(0x111, 0xf) KSTAGE(0x112, 0xf) KSTAGE(0x114, 0xf)
        KSTAGE(0x118, 0xf) KSTAGE(0x142, 0xa) KSTAGE(0x143, 0xc)
#undef KSTAGE
#pragma unroll
        for (int r = 0; r < 4; ++r) {
            unsigned g = (unsigned)__builtin_amdgcn_readlane((int)gv[r], 63);
            float w = __expf(-10.0f * __uint_as_float(g));
            unsigned long long mask = __ballot(bv[r] == g);
            int wl = __ffsll(mask) - 1;
            if (lane == wl) {
                float h0, h1;
                if (key[r][0] == g)      { h0 = hs[0].x; h1 = hs[0].y; key[r][0] = 0xFFFFFFFFu; }
                else if (key[r][1] == g) { h0 = hs[1].x; h1 = hs[1].y; key[r][1] = 0xFFFFFFFFu; }
                else if (key[r][2] == g) { h0 = hs[2].x; h1 = hs[2].y; key[r][2] = 0xFFFFFFFFu; }
                else                     { h0 = hs[3].x; h1 = hs[3].y; key[r][3] = 0xFFFFFFFFu; }
                acc0[r] = fmaf(w, h0, acc0[r]);
                acc1[r] = fmaf(w, h1, acc1[r]);
            }
        }
    }
#define SSTAGE(ctrl, rmask) { \
    DPP_ADD(acc0[0], ctrl, rmask) DPP_ADD(acc1[0], ctrl, rmask) \
    DPP_ADD(acc0[1], ctrl, rmask) DPP_ADD(acc1[1], ctrl, rmask) \
    DPP_ADD(acc0[2], ctrl, rmask) DPP_ADD(acc1[2], ctrl, rmask) \
    DPP_ADD(acc0[3], ctrl, rmask) DPP_ADD(acc1[3], ctrl, rmask) }
    SSTAGE(0x111, 0xf) SSTAGE(0x112, 0xf) SSTAGE(0x114, 0xf)
    SSTAGE(0x118, 0xf) SSTAGE(0x142, 0xa) SSTAGE(0x143, 0xc)
#undef SSTAGE
    if (lane == 63) {
#pragma unroll
        for (int r = 0; r < 4; ++r) {
            agg[(growbase + rbase + r) * 2 + 0] = acc0[r];
            agg[(growbase + rbase + r) * 2 + 1] = acc1[r];
        }
    }
}

struct Params {
    const float *X;
    const float *Ws1, *bs1, *Wh1, *bh1, *Wo1, *bo1;
    const float *Ws2, *bs2, *Wh2, *bh2, *Wo2, *bo2;
    const float *Ws3, *bs3, *Wh3, *bh3, *Wo3, *bo3;
    ushort *Wt1hi, *Wt1lo, *Wt2hi, *Wt2lo, *Xhi, *Xlo, *h1hi, *h1lo;
    float *s2, *hp2, *s3, *hp3, *aggb, *h2c, *out;
    unsigned *bar;   // [0]=cnt [1]=gen, memset to 0 before launch
};

// ---- device-wide barrier: ONE agent-scope fence per block (fences are cache-wide) ----
__device__ __forceinline__ void gridbar(unsigned* bar) {
    __syncthreads();                       // drains the block's stores (waitcnt)
    if (threadIdx.x == 0) {
        __threadfence();                   // agent release: writes back this XCD's L2
        unsigned g = __hip_atomic_load(&bar[1], __ATOMIC_RELAXED, __HIP_MEMORY_SCOPE_AGENT);
        unsigned a = __hip_atomic_fetch_add(&bar[0], 1u, __ATOMIC_ACQ_REL, __HIP_MEMORY_SCOPE_AGENT);
        if (a == NBLK - 1) {
            __hip_atomic_store(&bar[0], 0u, __ATOMIC_RELAXED, __HIP_MEMORY_SCOPE_AGENT);
            __hip_atomic_fetch_add(&bar[1], 1u, __ATOMIC_ACQ_REL, __HIP_MEMORY_SCOPE_AGENT);
        } else {
            while (__hip_atomic_load(&bar[1], __ATOMIC_RELAXED, __HIP_MEMORY_SCOPE_AGENT) == g)
                __builtin_amdgcn_s_sleep(2);
        }
        __threadfence();                   // agent acquire: invalidates this CU's L1 / XCD L2
    }
    __syncthreads();
}

// ---- gemm phase: 64x64 tile, 4 waves (2x2), split-bf16 MFMA, fused s/h partials ----
template<int K, int CMODE>
__device__ __forceinline__ void gemm_phase(
    const ushort* __restrict__ Ahi, const ushort* __restrict__ Alo,
    const ushort* __restrict__ Bhi, const ushort* __restrict__ Blo,
    const float* __restrict__ Wfull, const float* __restrict__ bias,
    const float* __restrict__ agg,
    float* __restrict__ Cf, ushort* __restrict__ Chi, ushort* __restrict__ Clo,
    const float* __restrict__ Wsn, const float* __restrict__ Whn,
    float* __restrict__ s_out, float* __restrict__ h_out,
    int bid, int tid, float* CT, float* part)
{
    const int lane = tid & 63, wid = tid >> 6;
    const int wm = wid >> 1, wn = wid & 1;
    const int m0 = (bid & 127) * 64, n0 = (bid >> 7) * 64;

    f32x4 acc[2][2];
#pragma unroll
    for (int mi = 0; mi < 2; ++mi)
#pragma unroll
        for (int ni = 0; ni < 2; ++ni)
            acc[mi][ni] = (f32x4){0.f, 0.f, 0.f, 0.f};

#pragma unroll 2
    for (int kof = 0; kof < K; kof += 32) {
        int kch = kof + (lane >> 4) * 8;
        bf16x8 ah[2], al[2], bh[2], bl[2];
#pragma unroll
        for (int mi = 0; mi < 2; ++mi) {
            size_t off = (size_t)(m0 + wm * 32 + mi * 16 + (lane & 15)) * K + kch;
            ah[mi] = ld8(Ahi + off); al[mi] = ld8(Alo + off);
        }
#pragma unroll
        for (int ni = 0; ni < 2; ++ni) {
            size_t off = (size_t)(n0 + wn * 32 + ni * 16 + (lane & 15)) * K + kch;
            bh[ni] = ld8(Bhi + off); bl[ni] = ld8(Blo + off);
        }
#pragma unroll
        for (int mi = 0; mi < 2; ++mi)
#pragma unroll
            for (int ni = 0; ni < 2; ++ni) {
                acc[mi][ni] = __builtin_amdgcn_mfma_f32_16x16x32_bf16(ah[mi], bh[ni], acc[mi][ni], 0, 0, 0);
                acc[mi][ni] = __builtin_amdgcn_mfma_f32_16x16x32_bf16(ah[mi], bl[ni], acc[mi][ni], 0, 0, 0);
                acc[mi][ni] = __builtin_amdgcn_mfma_f32_16x16x32_bf16(al[mi], bh[ni], acc[mi][ni], 0, 0, 0);
            }
    }

    // epilogue: + agg@Wa + bias, leaky, park in CT (C/D map: col=lane&15, row=(lane>>4)*4+r)
#pragma unroll
    for (int ni = 0; ni < 2; ++ni) {
        int nl = wn * 32 + ni * 16 + (lane & 15);
        int n = n0 + nl;
        float w0 = Wfull[n], w1 = Wfull[256 + n], bz = bias[n];
#pragma unroll
        for (int mi = 0; mi < 2; ++mi) {
            int mb = wm * 32 + mi * 16 + ((lane >> 4) << 2);
#pragma unroll
            for (int r = 0; r < 4; ++r) {
                int ml = mb + r, m = m0 + ml;
                float v = acc[mi][ni][r] + fmaf(agg[m * 2 + 0], w0, fmaf(agg[m * 2 + 1], w1, bz));
                v = v >= 0.f ? v : 0.01f * v;
                CT[ml * CTS + nl] = v;
                if (CMODE == 1 && (m & 255) == 0) Cf[(m >> 8) * 256 + n] = v;
            }
        }
    }
    __syncthreads();

    if (CMODE == 0) {   // coalesced split-plane write: 16 cols/thread
        int row = tid >> 2, cbase = (tid & 3) * 16;
        size_t m = (size_t)(m0 + row);
#pragma unroll
        for (int j = 0; j < 2; ++j) {
            int c = cbase + j * 8;
            ushort hi[8], lo[8];
#pragma unroll
            for (int t = 0; t < 8; ++t) {
                float v = CT[row * CTS + c + t];
                hi[t] = f2bf(v);
                lo[t] = f2bf(v - bf2f(hi[t]));
            }
            uint4 wh = make_uint4(pack2(hi[0], hi[1]), pack2(hi[2], hi[3]),
                                  pack2(hi[4], hi[5]), pack2(hi[6], hi[7]));
            uint4 wl = make_uint4(pack2(lo[0], lo[1]), pack2(lo[2], lo[3]),
                                  pack2(lo[4], lo[5]), pack2(lo[6], lo[7]));
            *reinterpret_cast<uint4*>(&Chi[m * 256 + n0 + c]) = wh;
            *reinterpret_cast<uint4*>(&Clo[m * 256 + n0 + c]) = wl;
        }
    }

    // fused next-layer s/h partials over this tile's 64 cols
    {
        int row = tid & 63, sub = tid >> 6;   // 4 subs x 16 cols
        float p0 = 0.f, p1 = 0.f, p2 = 0.f, p3 = 0.f, p4 = 0.f;
#pragma unroll
        for (int i = 0; i < 16; ++i) {
            int c = sub * 16 + i;
            float v = CT[row * CTS + c];
            int n = n0 + c;
            p0 = fmaf(v, Wsn[n * 3 + 0], p0);
            p1 = fmaf(v, Wsn[n * 3 + 1], p1);
            p2 = fmaf(v, Wsn[n * 3 + 2], p2);
            p3 = fmaf(v, Whn[n * 2 + 0], p3);
            p4 = fmaf(v, Whn[n * 2 + 1], p4);
        }
        float* pp = &part[(row * 4 + sub) * 5];
        pp[0] = p0; pp[1] = p1; pp[2] = p2; pp[3] = p3; pp[4] = p4;
    }
    __syncthreads();
    // block-stride over all 320 (row,o) pairs — blockDim is 256
    for (int u = tid; u < 320; u += 256) {
        int row = u / 5, o = u - row * 5;
        float sum = 0.f;
#pragma unroll
        for (int k = 0; k < 4; ++k) sum += part[(row * 4 + k) * 5 + o];
        if (o < 3) atomicAdd(&s_out[(m0 + row) * 3 + o], sum);
        else       atomicAdd(&h_out[(m0 + row) * 2 + (o - 3)], sum);
    }
}

// ================= THE mega kernel =================
__global__ __launch_bounds__(256, 2) void mega(Params p)
{
    __shared__ float smem[64 * CTS + 64 * 4 * 5];   // CT + part; sh5/pm alias CT region
    float* CT   = smem;
    float* part = smem + 64 * CTS;
    float* sh5  = smem;

    const int bid = blockIdx.x, tid = threadIdx.x;
    const int lane = tid & 63, wid = tid >> 6;

    // ---------- Phase A ----------
    {
        int g = bid & 31, chunk = bid >> 5;
        {   // in-block sh1 for whole graph (redundant x16)
            const float* xr = p.X + ((size_t)g * GN + tid) * 64;
            float a0 = 0.f, a1 = 0.f, a2 = 0.f, a3 = 0.f, a4 = 0.f;
#pragma unroll 4
            for (int c0 = 0; c0 < 64; c0 += 4) {
                float4 v = *reinterpret_cast<const float4*>(&xr[c0]);
                float xv[4] = {v.x, v.y, v.z, v.w};
#pragma unroll
                for (int j = 0; j < 4; ++j) {
                    int c = c0 + j;
                    a0 = fmaf(xv[j], p.Ws1[c * 3 + 0], a0);
                    a1 = fmaf(xv[j], p.Ws1[c * 3 + 1], a1);
                    a2 = fmaf(xv[j], p.Ws1[c * 3 + 2], a2);
                    a3 = fmaf(xv[j], p.Wh1[c * 2 + 0], a3);
                    a4 = fmaf(xv[j], p.Wh1[c * 2 + 1], a4);
                }
            }
            sh5[tid * 5 + 0] = a0 + p.bs1[0];
            sh5[tid * 5 + 1] = a1 + p.bs1[1];
            sh5[tid * 5 + 2] = a2 + p.bs1[2];
            sh5[tid * 5 + 3] = a3 + p.bh1[0];
            sh5[tid * 5 + 4] = a4 + p.bh1[1];
        }
        __syncthreads();
        knn_rows4(sh5, chunk * 16 + wid * 4, lane, g * GN, p.aggb);

        int gtid = bid * 256 + tid;               // 0..131071
        {   // X hi/lo split: 4 floats/thread
            float4 v = *reinterpret_cast<const float4*>(&p.X[(size_t)gtid * 4]);
            ushort4 hi, lo;
            hi.x = f2bf(v.x); lo.x = f2bf(v.x - bf2f(hi.x));
            hi.y = f2bf(v.y); lo.y = f2bf(v.y - bf2f(hi.y));
            hi.z = f2bf(v.z); lo.z = f2bf(v.z - bf2f(hi.z));
            hi.w = f2bf(v.w); lo.w = f2bf(v.w - bf2f(hi.w));
            *reinterpret_cast<ushort4*>(&p.Xhi[(size_t)gtid * 4]) = hi;
            *reinterpret_cast<ushort4*>(&p.Xlo[(size_t)gtid * 4]) = lo;
        }
        if (gtid < 81920) {   // weight split/transpose
            if (gtid < 65536) {
                int n = gtid >> 8, c = gtid & 255;
                float v = p.Wo2[(size_t)(2 + c) * 256 + n];
                ushort hi = f2bf(v);
                p.Wt2hi[n * 256 + c] = hi;
                p.Wt2lo[n * 256 + c] = f2bf(v - bf2f(hi));
            } else {
                int u = gtid - 65536;
                int n = u >> 6, c = u & 63;
                float v = p.Wo1[(size_t)(2 + c) * 256 + n];
                ushort hi = f2bf(v);
                p.Wt1hi[n * 64 + c] = hi;
                p.Wt1lo[n * 64 + c] = f2bf(v - bf2f(hi));
            }
            // bias-init of s/h accumulators
            if (gtid < 24576)      p.s2[gtid] = p.bs2[gtid % 3];
            else if (gtid < 40960) { int w = gtid - 24576; p.hp2[w] = p.bh2[w & 1]; }
            else if (gtid < 65536) { int w = gtid - 40960; p.s3[w] = p.bs3[w % 3]; }
            else                   { int w = gtid - 65536; p.hp3[w] = p.bh3[w & 1]; }
        }
    }
    gridbar(p.bar);

    // ---------- Phase B: gemm1 (K=64) ----------
    gemm_phase<64, 0>(p.Xhi, p.Xlo, p.Wt1hi, p.Wt1lo, p.Wo1, p.bo1, p.aggb,
                      nullptr, p.h1hi, p.h1lo, p.Ws2, p.Wh2, p.s2, p.hp2,
                      bid, tid, CT, part);
    gridbar(p.bar);

    // ---------- Phase C: knn2 ----------
    {
        int g = bid & 31, chunk = bid >> 5;
        int node = g * GN + tid;
        sh5[tid * 5 + 0] = p.s2[node * 3 + 0];
        sh5[tid * 5 + 1] = p.s2[node * 3 + 1];
        sh5[tid * 5 + 2] = p.s2[node * 3 + 2];
        sh5[tid * 5 + 3] = p.hp2[node * 2 + 0];
        sh5[tid * 5 + 4] = p.hp2[node * 2 + 1];
        __syncthreads();
        knn_rows4(sh5, chunk * 16 + wid * 4, lane, g * GN, p.aggb);
    }
    gridbar(p.bar);

    // ---------- Phase D: gemm2 (K=256) ----------
    gemm_phase<256, 1>(p.h1hi, p.h1lo, p.Wt2hi, p.Wt2lo, p.Wo2, p.bo2, p.aggb,
                       p.h2c, nullptr, nullptr, p.Ws3, p.Wh3, p.s3, p.hp3,
                       bid, tid, CT, part);
    gridbar(p.bar);

    // ---------- Phase E: knn3 + final (blocks 0..31) ----------
    if (bid < NGRAPH) {
        float* pm   = smem;        // [8][32]
        float* aggL = smem + 256;  // [2]
        int g = bid;
        if (tid < 64) {
            int base = g * GN, row = g * GN;
            float s0 = p.s3[row * 3 + 0], s1v = p.s3[row * 3 + 1], s2v = p.s3[row * 3 + 2];
            float s2row = s0 * s0 + s1v * s1v + s2v * s2v;
            unsigned key[4]; float2 hs[4];
#pragma unroll
            for (int t = 0; t < 4; ++t) {
                int j = base + lane + 64 * t;
                float x = p.s3[j * 3 + 0], y = p.s3[j * 3 + 1], z = p.s3[j * 3 + 2];
                float dot = s0 * x + s1v * y + s2v * z;
                float d2 = s2row + (x * x + y * y + z * z) - 2.0f * dot;
                key[t] = __float_as_uint(d2 > 0.f ? d2 : 0.f);
                hs[t] = *reinterpret_cast<const float2*>(&p.hp3[(size_t)j * 2]);
            }
            float a0, a1;
            knn_extract(key[0], key[1], key[2], key[3], hs[0], hs[1], hs[2], hs[3], lane, a0, a1);
            if (lane == 63) { aggL[0] = a0; aggL[1] = a1; }
        }
        __syncthreads();
        int o = tid & 31, seg = tid >> 5;
        const float* xr = p.h2c + g * 256;
        float pv = 0.f;
#pragma unroll
        for (int i = 0; i < 32; ++i) {
            int c = seg * 32 + i;
            pv = fmaf(xr[c], p.Wo3[(2 + c) * 32 + o], pv);
        }
        pm[seg * 32 + o] = pv;
        __syncthreads();
        if (tid < 32) {
            float acc = fmaf(aggL[0], p.Wo3[o], fmaf(aggL[1], p.Wo3[32 + o], p.bo3[o]));
#pragma unroll
            for (int k = 0; k < 8; ++k) acc += pm[k * 32 + o];
            p.out[g * 32 + o] = acc;
        }
    }
}

extern "C" void kernel_launch(void* const* d_in, const int* in_sizes, int n_in,
                              void* d_out, int out_size, void* d_ws, size_t ws_size,
                              hipStream_t stream) {
    Params p;
    p.X   = (const float*)d_in[0];
    p.Ws1 = (const float*)d_in[2];  p.bs1 = (const float*)d_in[3];
    p.Wh1 = (const float*)d_in[4];  p.bh1 = (const float*)d_in[5];
    p.Wo1 = (const float*)d_in[6];  p.bo1 = (const float*)d_in[7];
    p.Ws2 = (const float*)d_in[8];  p.bs2 = (const float*)d_in[9];
    p.Wh2 = (const float*)d_in[10]; p.bh2 = (const float*)d_in[11];
    p.Wo2 = (const float*)d_in[12]; p.bo2 = (const float*)d_in[13];
    p.Ws3 = (const float*)d_in[14]; p.bs3 = (const float*)d_in[15];
    p.Wh3 = (const float*)d_in[16]; p.bh3 = (const float*)d_in[17];
    p.Wo3 = (const float*)d_in[18]; p.bo3 = (const float*)d_in[19];

    char* w = (char*)d_ws;
    p.bar  = (unsigned*)w;            w += 256;                      // barrier state (+pad)
    p.s2   = (float*)w;               w += (size_t)NTOT * 3 * 4;
    p.hp2  = (float*)w;               w += (size_t)NTOT * 2 * 4;
    p.s3   = (float*)w;               w += (size_t)NTOT * 3 * 4;
    p.hp3  = (float*)w;               w += (size_t)NTOT * 2 * 4;
    p.aggb = (float*)w;               w += (size_t)NTOT * 2 * 4;
    p.h2c  = (float*)w;               w += (size_t)32 * 256 * 4;
    p.Xhi  = (ushort*)w;              w += (size_t)NTOT * 64 * 2;
    p.Xlo  = (ushort*)w;              w += (size_t)NTOT * 64 * 2;
    p.h1hi = (ushort*)w;              w += (size_t)NTOT * 256 * 2;
    p.h1lo = (ushort*)w;              w += (size_t)NTOT * 256 * 2;
    p.Wt1hi = (ushort*)w;             w += 256 * 64 * 2;
    p.Wt1lo = (ushort*)w;             w += 256 * 64 * 2;
    p.Wt2hi = (ushort*)w;             w += 256 * 256 * 2;
    p.Wt2lo = (ushort*)w;             w += 256 * 256 * 2;
    p.out  = (float*)d_out;

    hipMemsetAsync(p.bar, 0, 8, stream);
    mega<<<NBLK, 256, 0, stream>>>(p);
}

// Round 12
// 110.016 us; speedup vs baseline: 2.6491x; 2.6491x over previous
//
#include <hip/hip_runtime.h>
#include <hip/hip_bf16.h>

// GravNet: 32 graphs x 256 nodes, IN=64, HID=256, OUT=32, K=20, SPACE=3, PROP=2
// 3-launch pipeline, ZERO intra-kernel cross-block sync (all handoffs = plain stores
// across kernel boundaries; per-block work is self-contained via locality/recompute):
//  K2 (256 blk x 512 thr): blocks 0..127: in-block sh1 (graph g) + kNN for OWN 64 rows
//     (agg in LDS) + gemm1 BM=64 BN=256 (A=in-block X split->LDS swz, B=in-block Wo1
//     split->LDS swz) + h1 bf16 planes + COMPLETE s2/hp2 rows (plain stores, no atomics).
//     blocks 128..255: rider = Wo2 -> Wt2 hi/lo split.
//  K3 (128 blk x 512 thr): load graph's s2/hp2 -> kNN own 64 rows -> gemm2 K=256
//     (A=h1 planes, B=Wt2 planes, global ld8) + h2c row + COMPLETE s3/hp3 rows.
//  K4 (32 blk x 256 thr): per-graph kNN of row g*256 + final 258->32 matvec.
// GEMM x-part: split-bf16 MFMA (hi/lo, 3 products) == fp32 precision.

#define NGRAPH 32
#define GN 256
#define NTOT (NGRAPH*GN) // 8192
#define KNN 20
#define CTS 257          // CT leading dim (floats): 257%32==1 -> conflict-free columns

typedef __attribute__((ext_vector_type(8))) short bf16x8;
typedef __attribute__((ext_vector_type(4))) float f32x4;

__device__ __forceinline__ ushort f2bf(float x) {
    union { float f; unsigned u; } a; a.f = x;
    unsigned r = a.u + 0x7FFFu + ((a.u >> 16) & 1u);   // RNE
    return (ushort)(r >> 16);
}
__device__ __forceinline__ float bf2f(ushort h) {
    union { unsigned u; float f; } b; b.u = ((unsigned)h) << 16;
    return b.f;
}
__device__ __forceinline__ bf16x8 ld8(const ushort* p) {
    return *reinterpret_cast<const bf16x8*>(p);
}
__device__ __forceinline__ unsigned pack2(ushort a, ushort b) {
    return (unsigned)a | ((unsigned)b << 16);
}

// ---- DPP primitives (VALU-only) ----
#define DPP_MIN(v, ctrl, rmask) { \
    unsigned _t = (unsigned)__builtin_amdgcn_update_dpp((int)(v), (int)(v), ctrl, rmask, 0xf, false); \
    (v) = _t < (v) ? _t : (v); }
#define DPP_ADD(v, ctrl, rmask) { \
    float _t = __int_as_float(__builtin_amdgcn_update_dpp(0, __float_as_int(v), ctrl, rmask, 0xf, true)); \
    (v) += _t; }
__device__ __forceinline__ unsigned wave_min_u32(unsigned v) {
    DPP_MIN(v, 0x111, 0xf)
    DPP_MIN(v, 0x112, 0xf)
    DPP_MIN(v, 0x114, 0xf)
    DPP_MIN(v, 0x118, 0xf)
    DPP_MIN(v, 0x142, 0xa)
    DPP_MIN(v, 0x143, 0xc)
    return (unsigned)__builtin_amdgcn_readlane((int)v, 63);
}
__device__ __forceinline__ float wave_sum_f32(float v) {
    DPP_ADD(v, 0x111, 0xf)
    DPP_ADD(v, 0x112, 0xf)
    DPP_ADD(v, 0x114, 0xf)
    DPP_ADD(v, 0x118, 0xf)
    DPP_ADD(v, 0x142, 0xa)
    DPP_ADD(v, 0x143, 0xc)
    return __int_as_float(__builtin_amdgcn_readlane(__float_as_int(v), 63));
}

// ---- serial kNN extraction (K4 only) ----
__device__ __forceinline__ void knn_extract(
    unsigned ua, unsigned ub, unsigned uc, unsigned ud,
    float2 hA, float2 hB, float2 hC, float2 hD,
    int lane, float& out0, float& out1)
{
    float acc0 = 0.f, acc1 = 0.f;
#pragma unroll 1
    for (int it = 0; it < KNN; ++it) {
        unsigned m1 = ua < ub ? ua : ub;
        unsigned m2 = uc < ud ? uc : ud;
        unsigned bv = m1 < m2 ? m1 : m2;
        unsigned gv = wave_min_u32(bv);
        float d2 = __uint_as_float(gv);
        float w = __expf(-10.0f * d2);
        unsigned long long mask = __ballot(bv == gv);
        int wl = __ffsll(mask) - 1;
        if (lane == wl) {
            float h0, h1;
            if (ua == gv)      { h0 = hA.x; h1 = hA.y; ua = 0xFFFFFFFFu; }
            else if (ub == gv) { h0 = hB.x; h1 = hB.y; ub = 0xFFFFFFFFu; }
            else if (uc == gv) { h0 = hC.x; h1 = hC.y; uc = 0xFFFFFFFFu; }
            else               { h0 = hD.x; h1 = hD.y; ud = 0xFFFFFFFFu; }
            acc0 = fmaf(w, h0, acc0);
            acc1 = fmaf(w, h1, acc1);
        }
    }
    out0 = wave_sum_f32(acc0);
    out1 = wave_sum_f32(acc1);
}

// ---- 4 kNN rows per wave (ILP-interleaved chains); sh5 = [256][5] LDS; out -> aggL LDS --
__device__ __forceinline__ void knn_rows4(
    const float* sh5, int srow, int orow, int lane, float* __restrict__ aggL)
{
    float sjx[4], sjy[4], sjz[4], s2j[4];
    float2 hs[4];
#pragma unroll
    for (int t = 0; t < 4; ++t) {
        int j = lane + 64 * t;
        float x = sh5[j * 5 + 0], y = sh5[j * 5 + 1], z = sh5[j * 5 + 2];
        sjx[t] = x; sjy[t] = y; sjz[t] = z;
        s2j[t] = x * x + y * y + z * z;
        hs[t] = make_float2(sh5[j * 5 + 3], sh5[j * 5 + 4]);
    }
    unsigned key[4][4];
    float acc0[4], acc1[4];
#pragma unroll
    for (int r = 0; r < 4; ++r) {
        int rl = srow + r;
        float s0 = sh5[rl * 5 + 0], s1v = sh5[rl * 5 + 1], s2v = sh5[rl * 5 + 2];
        float s2row = s0 * s0 + s1v * s1v + s2v * s2v;
#pragma unroll
        for (int t = 0; t < 4; ++t) {
            float dot = s0 * sjx[t] + s1v * sjy[t] + s2v * sjz[t];
            float d2 = s2row + s2j[t] - 2.0f * dot;
            key[r][t] = __float_as_uint(d2 > 0.f ? d2 : 0.f);
        }
        acc0[r] = 0.f; acc1[r] = 0.f;
    }
#pragma unroll 1
    for (int it = 0; it < KNN; ++it) {
        unsigned bv[4], gv[4];
#pragma unroll
        for (int r = 0; r < 4; ++r) {
            unsigned m1 = key[r][0] < key[r][1] ? key[r][0] : key[r][1];
            unsigned m2 = key[r][2] < key[r][3] ? key[r][2] : key[r][3];
            bv[r] = m1 < m2 ? m1 : m2;
            gv[r] = bv[r];
        }
#define KSTAGE(ctrl, rmask) { \
        DPP_MIN(gv[0], ctrl, rmask) DPP_MIN(gv[1], ctrl, rmask) \
        DPP_MIN(gv[2], ctrl, rmask) DPP_MIN(gv[3], ctrl, rmask) }
        KSTAGE(0x111, 0xf) KSTAGE(0x112, 0xf) KSTAGE(0x114, 0xf)
        KSTAGE(0x118, 0xf) KSTAGE(0x142, 0xa) KSTAGE(0x143, 0xc)
#undef KSTAGE
#pragma unroll
        for (int r = 0; r < 4; ++r) {
            unsigned g = (unsigned)__builtin_amdgcn_readlane((int)gv[r], 63);
            float w = __expf(-10.0f * __uint_as_float(g));
            unsigned long long mask = __ballot(bv[r] == g);
            int wl = __ffsll(mask) - 1;
            if (lane == wl) {
                float h0, h1;
                if (key[r][0] == g)      { h0 = hs[0].x; h1 = hs[0].y; key[r][0] = 0xFFFFFFFFu; }
                else if (key[r][1] == g) { h0 = hs[1].x; h1 = hs[1].y; key[r][1] = 0xFFFFFFFFu; }
                else if (key[r][2] == g) { h0 = hs[2].x; h1 = hs[2].y; key[r][2] = 0xFFFFFFFFu; }
                else                     { h0 = hs[3].x; h1 = hs[3].y; key[r][3] = 0xFFFFFFFFu; }
                acc0[r] = fmaf(w, h0, acc0[r]);
                acc1[r] = fmaf(w, h1, acc1[r]);
            }
        }
    }
#define SSTAGE(ctrl, rmask) { \
    DPP_ADD(acc0[0], ctrl, rmask) DPP_ADD(acc1[0], ctrl, rmask) \
    DPP_ADD(acc0[1], ctrl, rmask) DPP_ADD(acc1[1], ctrl, rmask) \
    DPP_ADD(acc0[2], ctrl, rmask) DPP_ADD(acc1[2], ctrl, rmask) \
    DPP_ADD(acc0[3], ctrl, rmask) DPP_ADD(acc1[3], ctrl, rmask) }
    SSTAGE(0x111, 0xf) SSTAGE(0x112, 0xf) SSTAGE(0x114, 0xf)
    SSTAGE(0x118, 0xf) SSTAGE(0x142, 0xa) SSTAGE(0x143, 0xc)
#undef SSTAGE
    if (lane == 63) {
#pragma unroll
        for (int r = 0; r < 4; ++r) {
            aggL[(orow + r) * 2 + 0] = acc0[r];
            aggL[(orow + r) * 2 + 1] = acc1[r];
        }
    }
}

// ================= K2: sh1 + knn1 + gemm1 (BN=256) + s2/hp2 | Wt2 rider =================
__global__ __launch_bounds__(512) void k2_fused(
    const float* __restrict__ X,
    const float* __restrict__ Ws1, const float* __restrict__ bs1,
    const float* __restrict__ Wh1, const float* __restrict__ bh1,
    const float* __restrict__ Wo1, const float* __restrict__ bo1,
    const float* __restrict__ Ws2, const float* __restrict__ Wh2,
    const float* __restrict__ bs2, const float* __restrict__ bh2,
    const float* __restrict__ Wo2,
    ushort* __restrict__ Wt2hi, ushort* __restrict__ Wt2lo,
    ushort* __restrict__ h1hi, ushort* __restrict__ h1lo,
    float* __restrict__ s2, float* __restrict__ hp2)
{
    const int x = blockIdx.x, tid = threadIdx.x;
    if (x >= 128) {                        // ---- rider: Wo2[2+c][n] -> Wt2[n][c] hi/lo
        int t = (x - 128) * 512 + tid;     // 0..65535
        int n = t >> 8, c = t & 255;
        float v = Wo2[(size_t)(2 + c) * 256 + n];
        ushort hi = f2bf(v);
        Wt2hi[n * 256 + c] = hi;
        Wt2lo[n * 256 + c] = f2bf(v - bf2f(hi));
        return;
    }
    __shared__ float sh5[256 * 5];                 // graph s/h (stride 5)
    __shared__ float aggL[64 * 2];                 // this block's 64 agg rows
    __shared__ ushort Ahi[64 * 64], Alo[64 * 64];  // X tile, swizzled
    __shared__ float BCT[64 * CTS];                // union: Bhi/Blo then CT
    __shared__ float part[64 * 8 * 5];
    ushort* Bhi = (ushort*)BCT;
    ushort* Blo = Bhi + 256 * 64;
    float*  CT  = BCT;

    const int lane = tid & 63, wid = tid >> 6;
    const int g = x >> 2, m0 = x * 64, lr0 = (x & 3) * 64;

    // sh1: project all 256 nodes of graph g (redundant x4 across sibling blocks)
    if (tid < 256) {
        const float* xr = X + ((size_t)g * GN + tid) * 64;
        float a0 = 0.f, a1 = 0.f, a2 = 0.f, a3 = 0.f, a4 = 0.f;
#pragma unroll 4
        for (int c0 = 0; c0 < 64; c0 += 4) {
            float4 v = *reinterpret_cast<const float4*>(&xr[c0]);
            float xv[4] = {v.x, v.y, v.z, v.w};
#pragma unroll
            for (int j = 0; j < 4; ++j) {
                int c = c0 + j;
                a0 = fmaf(xv[j], Ws1[c * 3 + 0], a0);
                a1 = fmaf(xv[j], Ws1[c * 3 + 1], a1);
                a2 = fmaf(xv[j], Ws1[c * 3 + 2], a2);
                a3 = fmaf(xv[j], Wh1[c * 2 + 0], a3);
                a4 = fmaf(xv[j], Wh1[c * 2 + 1], a4);
            }
        }
        sh5[tid * 5 + 0] = a0 + bs1[0];
        sh5[tid * 5 + 1] = a1 + bs1[1];
        sh5[tid * 5 + 2] = a2 + bs1[2];
        sh5[tid * 5 + 3] = a3 + bh1[0];
        sh5[tid * 5 + 4] = a4 + bh1[1];
    }
    // A-split: X rows m0..m0+63 -> Ahi/Alo (XOR-swizzled, R2-verified pattern)
#pragma unroll
    for (int i = 0; i < 2; ++i) {
        int lin = tid + i * 512;
        int row = lin >> 4, c4 = (lin & 15) * 4;
        float4 v = *reinterpret_cast<const float4*>(&X[(size_t)(m0 + row) * 64 + c4]);
        int idx = (row * 64 + c4) ^ ((row & 7) << 3);
        ushort4 hi, lo;
        hi.x = f2bf(v.x); lo.x = f2bf(v.x - bf2f(hi.x));
        hi.y = f2bf(v.y); lo.y = f2bf(v.y - bf2f(hi.y));
        hi.z = f2bf(v.z); lo.z = f2bf(v.z - bf2f(hi.z));
        hi.w = f2bf(v.w); lo.w = f2bf(v.w - bf2f(hi.w));
        *reinterpret_cast<ushort4*>(&Ahi[idx]) = hi;
        *reinterpret_cast<ushort4*>(&Alo[idx]) = lo;
    }
    // B-split: Wo1[2+c][n] -> Bhi/Blo [n][c], swizzled (coalesced global reads)
#pragma unroll 4
    for (int i = 0; i < 32; ++i) {
        int e = i * 512 + tid;
        int c = e >> 8, n = e & 255;
        float v = Wo1[(size_t)(2 + c) * 256 + n];
        int idx = (n * 64 + c) ^ ((n & 7) << 3);
        ushort hi = f2bf(v);
        Bhi[idx] = hi;
        Blo[idx] = f2bf(v - bf2f(hi));
    }
    __syncthreads();

    // knn1 for our 64 rows -> aggL
    knn_rows4(sh5, lr0 + wid * 4,      wid * 4,      lane, aggL);
    knn_rows4(sh5, lr0 + 32 + wid * 4, 32 + wid * 4, lane, aggL);

    // gemm1: BM=64, BN=256, K=64; 8 waves (2m x 4n), each 32x64
    const int wm = wid >> 2, wn = wid & 3;
    f32x4 acc[2][4];
#pragma unroll
    for (int mi = 0; mi < 2; ++mi)
#pragma unroll
        for (int ni = 0; ni < 4; ++ni)
            acc[mi][ni] = (f32x4){0.f, 0.f, 0.f, 0.f};
#pragma unroll
    for (int kof = 0; kof < 64; kof += 32) {
        int kch = kof + (lane >> 4) * 8;
        bf16x8 ah[2], al[2], bh[4], bl[4];
#pragma unroll
        for (int mi = 0; mi < 2; ++mi) {
            int r = wm * 32 + mi * 16 + (lane & 15);
            int idx = (r * 64 + kch) ^ ((r & 7) << 3);
            ah[mi] = ld8(&Ahi[idx]); al[mi] = ld8(&Alo[idx]);
        }
#pragma unroll
        for (int ni = 0; ni < 4; ++ni) {
            int n = wn * 64 + ni * 16 + (lane & 15);
            int idx = (n * 64 + kch) ^ ((n & 7) << 3);
            bh[ni] = ld8(&Bhi[idx]); bl[ni] = ld8(&Blo[idx]);
        }
#pragma unroll
        for (int mi = 0; mi < 2; ++mi)
#pragma unroll
            for (int ni = 0; ni < 4; ++ni) {
                acc[mi][ni] = __builtin_amdgcn_mfma_f32_16x16x32_bf16(ah[mi], bh[ni], acc[mi][ni], 0, 0, 0);
                acc[mi][ni] = __builtin_amdgcn_mfma_f32_16x16x32_bf16(ah[mi], bl[ni], acc[mi][ni], 0, 0, 0);
                acc[mi][ni] = __builtin_amdgcn_mfma_f32_16x16x32_bf16(al[mi], bh[ni], acc[mi][ni], 0, 0, 0);
            }
    }
    __syncthreads();   // B reads done (CT may overwrite); aggL complete

    // epilogue: + agg@Wa + bias, leaky -> CT. C/D map: col=lane&15, row=(lane>>4)*4+r
#pragma unroll
    for (int ni = 0; ni < 4; ++ni) {
        int n = wn * 64 + ni * 16 + (lane & 15);
        float w0 = Wo1[n], w1 = Wo1[256 + n], bz = bo1[n];
#pragma unroll
        for (int mi = 0; mi < 2; ++mi) {
            int mb = wm * 32 + mi * 16 + ((lane >> 4) << 2);
#pragma unroll
            for (int r = 0; r < 4; ++r) {
                int ml = mb + r;
                float v = acc[mi][ni][r] + fmaf(aggL[ml * 2 + 0], w0, fmaf(aggL[ml * 2 + 1], w1, bz));
                CT[ml * CTS + n] = v >= 0.f ? v : 0.01f * v;
            }
        }
    }
    __syncthreads();

    // h1 planes from CT (coalesced packed stores)
    {
        int row = tid >> 3, cb = (tid & 7) * 32;
        size_t m = (size_t)(m0 + row);
#pragma unroll
        for (int j = 0; j < 4; ++j) {
            int c = cb + j * 8;
            ushort hi[8], lo[8];
#pragma unroll
            for (int t = 0; t < 8; ++t) {
                float v = CT[row * CTS + c + t];
                hi[t] = f2bf(v);
                lo[t] = f2bf(v - bf2f(hi[t]));
            }
            uint4 wh = make_uint4(pack2(hi[0], hi[1]), pack2(hi[2], hi[3]),
                                  pack2(hi[4], hi[5]), pack2(hi[6], hi[7]));
            uint4 wl = make_uint4(pack2(lo[0], lo[1]), pack2(lo[2], lo[3]),
                                  pack2(lo[4], lo[5]), pack2(lo[6], lo[7]));
            *reinterpret_cast<uint4*>(&h1hi[m * 256 + c]) = wh;
            *reinterpret_cast<uint4*>(&h1lo[m * 256 + c]) = wl;
        }
    }
    // s2/hp2: full 256-col projections, complete rows (plain stores, no atomics)
    {
        int row = tid & 63, sub = tid >> 6;
        float p0 = 0.f, p1 = 0.f, p2 = 0.f, p3 = 0.f, p4 = 0.f;
#pragma unroll
        for (int i = 0; i < 32; ++i) {
            int c = sub * 32 + i;
            float v = CT[row * CTS + c];
            p0 = fmaf(v, Ws2[c * 3 + 0], p0);
            p1 = fmaf(v, Ws2[c * 3 + 1], p1);
            p2 = fmaf(v, Ws2[c * 3 + 2], p2);
            p3 = fmaf(v, Wh2[c * 2 + 0], p3);
            p4 = fmaf(v, Wh2[c * 2 + 1], p4);
        }
        float* pp = &part[(row * 8 + sub) * 5];
        pp[0] = p0; pp[1] = p1; pp[2] = p2; pp[3] = p3; pp[4] = p4;
    }
    __syncthreads();
    if (tid < 320) {
        int row = tid / 5, o = tid - row * 5;
        float sum = 0.f;
#pragma unroll
        for (int k = 0; k < 8; ++k) sum += part[(row * 8 + k) * 5 + o];
        if (o < 3) s2[(m0 + row) * 3 + o] = bs2[o] + sum;
        else       hp2[(m0 + row) * 2 + (o - 3)] = bh2[o - 3] + sum;
    }
}

// ================= K3: knn2 + gemm2 (K=256, BN=256) + h2c + s3/hp3 =================
__global__ __launch_bounds__(512) void k3_fused(
    const float* __restrict__ s2, const float* __restrict__ hp2,
    const ushort* __restrict__ h1hi, const ushort* __restrict__ h1lo,
    const ushort* __restrict__ Wt2hi, const ushort* __restrict__ Wt2lo,
    const float* __restrict__ Wo2, const float* __restrict__ bo2,
    const float* __restrict__ Ws3, const float* __restrict__ Wh3,
    const float* __restrict__ bs3, const float* __restrict__ bh3,
    float* __restrict__ h2c, float* __restrict__ s3, float* __restrict__ hp3)
{
    __shared__ float sh5[256 * 5];
    __shared__ float aggL[64 * 2];
    __shared__ float CT[64 * CTS];
    __shared__ float part[64 * 8 * 5];

    const int x = blockIdx.x, tid = threadIdx.x;
    const int lane = tid & 63, wid = tid >> 6;
    const int g = x >> 2, m0 = x * 64, lr0 = (x & 3) * 64;

    if (tid < 256) {
        int node = g * GN + tid;
        sh5[tid * 5 + 0] = s2[node * 3 + 0];
        sh5[tid * 5 + 1] = s2[node * 3 + 1];
        sh5[tid * 5 + 2] = s2[node * 3 + 2];
        sh5[tid * 5 + 3] = hp2[node * 2 + 0];
        sh5[tid * 5 + 4] = hp2[node * 2 + 1];
    }
    __syncthreads();
    knn_rows4(sh5, lr0 + wid * 4,      wid * 4,      lane, aggL);
    knn_rows4(sh5, lr0 + 32 + wid * 4, 32 + wid * 4, lane, aggL);
    __syncthreads();   // aggL complete before epilogue

    const int wm = wid >> 2, wn = wid & 3;
    f32x4 acc[2][4];
#pragma unroll
    for (int mi = 0; mi < 2; ++mi)
#pragma unroll
        for (int ni = 0; ni < 4; ++ni)
            acc[mi][ni] = (f32x4){0.f, 0.f, 0.f, 0.f};
#pragma unroll 2
    for (int kof = 0; kof < 256; kof += 32) {
        int kch = kof + (lane >> 4) * 8;
        bf16x8 ah[2], al[2], bh[4], bl[4];
#pragma unroll
        for (int mi = 0; mi < 2; ++mi) {
            size_t off = (size_t)(m0 + wm * 32 + mi * 16 + (lane & 15)) * 256 + kch;
            ah[mi] = ld8(h1hi + off); al[mi] = ld8(h1lo + off);
        }
#pragma unroll
        for (int ni = 0; ni < 4; ++ni) {
            size_t off = (size_t)(wn * 64 + ni * 16 + (lane & 15)) * 256 + kch;
            bh[ni] = ld8(Wt2hi + off); bl[ni] = ld8(Wt2lo + off);
        }
#pragma unroll
        for (int mi = 0; mi < 2; ++mi)
#pragma unroll
            for (int ni = 0; ni < 4; ++ni) {
                acc[mi][ni] = __builtin_amdgcn_mfma_f32_16x16x32_bf16(ah[mi], bh[ni], acc[mi][ni], 0, 0, 0);
                acc[mi][ni] = __builtin_amdgcn_mfma_f32_16x16x32_bf16(ah[mi], bl[ni], acc[mi][ni], 0, 0, 0);
                acc[mi][ni] = __builtin_amdgcn_mfma_f32_16x16x32_bf16(al[mi], bh[ni], acc[mi][ni], 0, 0, 0);
            }
    }

    // epilogue: + agg@Wa + bias, leaky -> CT
#pragma unroll
    for (int ni = 0; ni < 4; ++ni) {
        int n = wn * 64 + ni * 16 + (lane & 15);
        float w0 = Wo2[n], w1 = Wo2[256 + n], bz = bo2[n];
#pragma unroll
        for (int mi = 0; mi < 2; ++mi) {
            int mb = wm * 32 + mi * 16 + ((lane >> 4) << 2);
#pragma unroll
            for (int r = 0; r < 4; ++r) {
                int ml = mb + r;
                float v = acc[mi][ni][r] + fmaf(aggL[ml * 2 + 0], w0, fmaf(aggL[ml * 2 + 1], w1, bz));
                CT[ml * CTS + n] = v >= 0.f ? v : 0.01f * v;
            }
        }
    }
    __syncthreads();

    // h2c: first row of each graph (block x = 4g holds global row g*256 at ml=0)
    if ((x & 3) == 0 && tid < 256) h2c[g * 256 + tid] = CT[tid];

    // s3/hp3: full 256-col projections, complete rows
    {
        int row = tid & 63, sub = tid >> 6;
        float p0 = 0.f, p1 = 0.f, p2 = 0.f, p3 = 0.f, p4 = 0.f;
#pragma unroll
        for (int i = 0; i < 32; ++i) {
            int c = sub * 32 + i;
            float v = CT[row * CTS + c];
            p0 = fmaf(v, Ws3[c * 3 + 0], p0);
            p1 = fmaf(v, Ws3[c * 3 + 1], p1);
            p2 = fmaf(v, Ws3[c * 3 + 2], p2);
            p3 = fmaf(v, Wh3[c * 2 + 0], p3);
            p4 = fmaf(v, Wh3[c * 2 + 1], p4);
        }
        float* pp = &part[(row * 8 + sub) * 5];
        pp[0] = p0; pp[1] = p1; pp[2] = p2; pp[3] = p3; pp[4] = p4;
    }
    __syncthreads();
    if (tid < 320) {
        int row = tid / 5, o = tid - row * 5;
        float sum = 0.f;
#pragma unroll
        for (int k = 0; k < 8; ++k) sum += part[(row * 8 + k) * 5 + o];
        if (o < 3) s3[(m0 + row) * 3 + o] = bs3[o] + sum;
        else       hp3[(m0 + row) * 2 + (o - 3)] = bh3[o - 3] + sum;
    }
}

// ================= K4: per-graph kNN of row g*256 + final matvec =================
__global__ __launch_bounds__(256) void knn3_final(
    const float* __restrict__ s, const float* __restrict__ h,
    const float* __restrict__ h2c,
    const float* __restrict__ Wo, const float* __restrict__ bo,
    float* __restrict__ out)
{
    __shared__ float aggL[2];
    __shared__ float pm[8][32];
    int g = blockIdx.x, tid = threadIdx.x;
    if (tid < 64) {
        int lane = tid;
        int base = g * GN, row = g * GN;
        float s0 = s[row * 3 + 0], s1v = s[row * 3 + 1], s2v = s[row * 3 + 2];
        float s2row = s0 * s0 + s1v * s1v + s2v * s2v;
        unsigned key[4]; float2 hs[4];
#pragma unroll
        for (int t = 0; t < 4; ++t) {
            int j = base + lane + 64 * t;
            float xx = s[j * 3 + 0], y = s[j * 3 + 1], z = s[j * 3 + 2];
            float dot = s0 * xx + s1v * y + s2v * z;
            float d2 = s2row + (xx * xx + y * y + z * z) - 2.0f * dot;
            key[t] = __float_as_uint(d2 > 0.f ? d2 : 0.f);
            hs[t] = *reinterpret_cast<const float2*>(&h[(size_t)j * 2]);
        }
        float a0, a1;
        knn_extract(key[0], key[1], key[2], key[3], hs[0], hs[1], hs[2], hs[3], lane, a0, a1);
        if (lane == 63) { aggL[0] = a0; aggL[1] = a1; }
    }
    __syncthreads();
    int o = tid & 31, seg = tid >> 5;
    const float* xr = h2c + g * 256;
    float p = 0.f;
#pragma unroll
    for (int i = 0; i < 32; ++i) {
        int c = seg * 32 + i;
        p = fmaf(xr[c], Wo[(2 + c) * 32 + o], p);
    }
    pm[seg][o] = p;
    __syncthreads();
    if (tid < 32) {
        float acc = fmaf(aggL[0], Wo[o], fmaf(aggL[1], Wo[32 + o], bo[o]));
#pragma unroll
        for (int k = 0; k < 8; ++k) acc += pm[k][o];
        out[g * 32 + o] = acc;
    }
}

extern "C" void kernel_launch(void* const* d_in, const int* in_sizes, int n_in,
                              void* d_out, int out_size, void* d_ws, size_t ws_size,
                              hipStream_t stream) {
    const float* X   = (const float*)d_in[0];
    const float* Ws1 = (const float*)d_in[2];  const float* bs1 = (const float*)d_in[3];
    const float* Wh1 = (const float*)d_in[4];  const float* bh1 = (const float*)d_in[5];
    const float* Wo1 = (const float*)d_in[6];  const float* bo1 = (const float*)d_in[7];
    const float* Ws2 = (const float*)d_in[8];  const float* bs2 = (const float*)d_in[9];
    const float* Wh2 = (const float*)d_in[10]; const float* bh2 = (const float*)d_in[11];
    const float* Wo2 = (const float*)d_in[12]; const float* bo2 = (const float*)d_in[13];
    const float* Ws3 = (const float*)d_in[14]; const float* bs3 = (const float*)d_in[15];
    const float* Wh3 = (const float*)d_in[16]; const float* bh3 = (const float*)d_in[17];
    const float* Wo3 = (const float*)d_in[18]; const float* bo3 = (const float*)d_in[19];

    float* p = (float*)d_ws;
    float* s2   = p; p += NTOT * 3;
    float* hp2  = p; p += NTOT * 2;
    float* s3   = p; p += NTOT * 3;
    float* hp3  = p; p += NTOT * 2;
    float* h2c  = p; p += 32 * 256;
    ushort* q = (ushort*)p;
    ushort* h1hi = q; q += (size_t)NTOT * 256;
    ushort* h1lo = q; q += (size_t)NTOT * 256;
    ushort* Wt2hi = q; q += 256 * 256;
    ushort* Wt2lo = q; q += 256 * 256;

    k2_fused<<<256, 512, 0, stream>>>(X, Ws1, bs1, Wh1, bh1, Wo1, bo1,
                                      Ws2, Wh2, bs2, bh2, Wo2,
                                      Wt2hi, Wt2lo, h1hi, h1lo, s2, hp2);
    k3_fused<<<128, 512, 0, stream>>>(s2, hp2, h1hi, h1lo, Wt2hi, Wt2lo,
                                      Wo2, bo2, Ws3, Wh3, bs3, bh3,
                                      h2c, s3, hp3);
    knn3_final<<<NGRAPH, 256, 0, stream>>>(s3, hp3, h2c, Wo3, bo3, (float*)d_out);
}

// Round 13
// 90.093 us; speedup vs baseline: 3.2349x; 1.2211x over previous
//
#include <hip/hip_runtime.h>
#include <hip/hip_bf16.h>

// GravNet: 32 graphs x 256 nodes, IN=64, HID=256, OUT=32, K=20, SPACE=3, PROP=2
// 3-launch pipeline, zero cross-block sync (handoffs = plain stores across kernel bounds):
//  K2 (256 blk x 512 thr): blocks 0..127: in-block sh1 + kNN own 64 rows + gemm1 BM=64
//     BN=256 (LDS-staged split operands) + h1 bf16 planes + complete s2/hp2 rows.
//     blocks 128..255: rider = Wo2 -> Wt2 hi/lo split.            [R12-verified, ~16us]
//  K3 (256 blk x 512 thr): BM=32 rows/block (R13 fix: was BM=64 x 128 blk at 80KB LDS ->
//     half machine + 1 blk/CU + 2x serial knn = 58us). Now: 1x knn_rows4/wave, gemm2
//     K=256 acc[2][2], LDS ~48KB -> 3 blk/CU, full coverage.
//  K4 (32 blk x 256 thr): per-graph kNN of row g*256 + final 258->32 matvec.
// GEMM x-part: split-bf16 MFMA (hi/lo, 3 products) == fp32 precision.

#define NGRAPH 32
#define GN 256
#define NTOT (NGRAPH*GN) // 8192
#define KNN 20
#define CTS 257          // CT leading dim (floats): 257%32==1 -> conflict-free columns

typedef __attribute__((ext_vector_type(8))) short bf16x8;
typedef __attribute__((ext_vector_type(4))) float f32x4;

__device__ __forceinline__ ushort f2bf(float x) {
    union { float f; unsigned u; } a; a.f = x;
    unsigned r = a.u + 0x7FFFu + ((a.u >> 16) & 1u);   // RNE
    return (ushort)(r >> 16);
}
__device__ __forceinline__ float bf2f(ushort h) {
    union { unsigned u; float f; } b; b.u = ((unsigned)h) << 16;
    return b.f;
}
__device__ __forceinline__ bf16x8 ld8(const ushort* p) {
    return *reinterpret_cast<const bf16x8*>(p);
}
__device__ __forceinline__ unsigned pack2(ushort a, ushort b) {
    return (unsigned)a | ((unsigned)b << 16);
}

// ---- DPP primitives (VALU-only) ----
#define DPP_MIN(v, ctrl, rmask) { \
    unsigned _t = (unsigned)__builtin_amdgcn_update_dpp((int)(v), (int)(v), ctrl, rmask, 0xf, false); \
    (v) = _t < (v) ? _t : (v); }
#define DPP_ADD(v, ctrl, rmask) { \
    float _t = __int_as_float(__builtin_amdgcn_update_dpp(0, __float_as_int(v), ctrl, rmask, 0xf, true)); \
    (v) += _t; }
__device__ __forceinline__ unsigned wave_min_u32(unsigned v) {
    DPP_MIN(v, 0x111, 0xf)
    DPP_MIN(v, 0x112, 0xf)
    DPP_MIN(v, 0x114, 0xf)
    DPP_MIN(v, 0x118, 0xf)
    DPP_MIN(v, 0x142, 0xa)
    DPP_MIN(v, 0x143, 0xc)
    return (unsigned)__builtin_amdgcn_readlane((int)v, 63);
}
__device__ __forceinline__ float wave_sum_f32(float v) {
    DPP_ADD(v, 0x111, 0xf)
    DPP_ADD(v, 0x112, 0xf)
    DPP_ADD(v, 0x114, 0xf)
    DPP_ADD(v, 0x118, 0xf)
    DPP_ADD(v, 0x142, 0xa)
    DPP_ADD(v, 0x143, 0xc)
    return __int_as_float(__builtin_amdgcn_readlane(__float_as_int(v), 63));
}

// ---- serial kNN extraction (K4 only) ----
__device__ __forceinline__ void knn_extract(
    unsigned ua, unsigned ub, unsigned uc, unsigned ud,
    float2 hA, float2 hB, float2 hC, float2 hD,
    int lane, float& out0, float& out1)
{
    float acc0 = 0.f, acc1 = 0.f;
#pragma unroll 1
    for (int it = 0; it < KNN; ++it) {
        unsigned m1 = ua < ub ? ua : ub;
        unsigned m2 = uc < ud ? uc : ud;
        unsigned bv = m1 < m2 ? m1 : m2;
        unsigned gv = wave_min_u32(bv);
        float d2 = __uint_as_float(gv);
        float w = __expf(-10.0f * d2);
        unsigned long long mask = __ballot(bv == gv);
        int wl = __ffsll(mask) - 1;
        if (lane == wl) {
            float h0, h1;
            if (ua == gv)      { h0 = hA.x; h1 = hA.y; ua = 0xFFFFFFFFu; }
            else if (ub == gv) { h0 = hB.x; h1 = hB.y; ub = 0xFFFFFFFFu; }
            else if (uc == gv) { h0 = hC.x; h1 = hC.y; uc = 0xFFFFFFFFu; }
            else               { h0 = hD.x; h1 = hD.y; ud = 0xFFFFFFFFu; }
            acc0 = fmaf(w, h0, acc0);
            acc1 = fmaf(w, h1, acc1);
        }
    }
    out0 = wave_sum_f32(acc0);
    out1 = wave_sum_f32(acc1);
}

// ---- 4 kNN rows per wave (ILP-interleaved chains); sh5 = [256][5] LDS; out -> aggL LDS --
__device__ __forceinline__ void knn_rows4(
    const float* sh5, int srow, int orow, int lane, float* __restrict__ aggL)
{
    float sjx[4], sjy[4], sjz[4], s2j[4];
    float2 hs[4];
#pragma unroll
    for (int t = 0; t < 4; ++t) {
        int j = lane + 64 * t;
        float x = sh5[j * 5 + 0], y = sh5[j * 5 + 1], z = sh5[j * 5 + 2];
        sjx[t] = x; sjy[t] = y; sjz[t] = z;
        s2j[t] = x * x + y * y + z * z;
        hs[t] = make_float2(sh5[j * 5 + 3], sh5[j * 5 + 4]);
    }
    unsigned key[4][4];
    float acc0[4], acc1[4];
#pragma unroll
    for (int r = 0; r < 4; ++r) {
        int rl = srow + r;
        float s0 = sh5[rl * 5 + 0], s1v = sh5[rl * 5 + 1], s2v = sh5[rl * 5 + 2];
        float s2row = s0 * s0 + s1v * s1v + s2v * s2v;
#pragma unroll
        for (int t = 0; t < 4; ++t) {
            float dot = s0 * sjx[t] + s1v * sjy[t] + s2v * sjz[t];
            float d2 = s2row + s2j[t] - 2.0f * dot;
            key[r][t] = __float_as_uint(d2 > 0.f ? d2 : 0.f);
        }
        acc0[r] = 0.f; acc1[r] = 0.f;
    }
#pragma unroll 1
    for (int it = 0; it < KNN; ++it) {
        unsigned bv[4], gv[4];
#pragma unroll
        for (int r = 0; r < 4; ++r) {
            unsigned m1 = key[r][0] < key[r][1] ? key[r][0] : key[r][1];
            unsigned m2 = key[r][2] < key[r][3] ? key[r][2] : key[r][3];
            bv[r] = m1 < m2 ? m1 : m2;
            gv[r] = bv[r];
        }
#define KSTAGE(ctrl, rmask) { \
        DPP_MIN(gv[0], ctrl, rmask) DPP_MIN(gv[1], ctrl, rmask) \
        DPP_MIN(gv[2], ctrl, rmask) DPP_MIN(gv[3], ctrl, rmask) }
        KSTAGE(0x111, 0xf) KSTAGE(0x112, 0xf) KSTAGE(0x114, 0xf)
        KSTAGE(0x118, 0xf) KSTAGE(0x142, 0xa) KSTAGE(0x143, 0xc)
#undef KSTAGE
#pragma unroll
        for (int r = 0; r < 4; ++r) {
            unsigned g = (unsigned)__builtin_amdgcn_readlane((int)gv[r], 63);
            float w = __expf(-10.0f * __uint_as_float(g));
            unsigned long long mask = __ballot(bv[r] == g);
            int wl = __ffsll(mask) - 1;
            if (lane == wl) {
                float h0, h1;
                if (key[r][0] == g)      { h0 = hs[0].x; h1 = hs[0].y; key[r][0] = 0xFFFFFFFFu; }
                else if (key[r][1] == g) { h0 = hs[1].x; h1 = hs[1].y; key[r][1] = 0xFFFFFFFFu; }
                else if (key[r][2] == g) { h0 = hs[2].x; h1 = hs[2].y; key[r][2] = 0xFFFFFFFFu; }
                else                     { h0 = hs[3].x; h1 = hs[3].y; key[r][3] = 0xFFFFFFFFu; }
                acc0[r] = fmaf(w, h0, acc0[r]);
                acc1[r] = fmaf(w, h1, acc1[r]);
            }
        }
    }
#define SSTAGE(ctrl, rmask) { \
    DPP_ADD(acc0[0], ctrl, rmask) DPP_ADD(acc1[0], ctrl, rmask) \
    DPP_ADD(acc0[1], ctrl, rmask) DPP_ADD(acc1[1], ctrl, rmask) \
    DPP_ADD(acc0[2], ctrl, rmask) DPP_ADD(acc1[2], ctrl, rmask) \
    DPP_ADD(acc0[3], ctrl, rmask) DPP_ADD(acc1[3], ctrl, rmask) }
    SSTAGE(0x111, 0xf) SSTAGE(0x112, 0xf) SSTAGE(0x114, 0xf)
    SSTAGE(0x118, 0xf) SSTAGE(0x142, 0xa) SSTAGE(0x143, 0xc)
#undef SSTAGE
    if (lane == 63) {
#pragma unroll
        for (int r = 0; r < 4; ++r) {
            aggL[(orow + r) * 2 + 0] = acc0[r];
            aggL[(orow + r) * 2 + 1] = acc1[r];
        }
    }
}

// ================= K2: sh1 + knn1 + gemm1 (BN=256) + s2/hp2 | Wt2 rider =================
__global__ __launch_bounds__(512) void k2_fused(
    const float* __restrict__ X,
    const float* __restrict__ Ws1, const float* __restrict__ bs1,
    const float* __restrict__ Wh1, const float* __restrict__ bh1,
    const float* __restrict__ Wo1, const float* __restrict__ bo1,
    const float* __restrict__ Ws2, const float* __restrict__ Wh2,
    const float* __restrict__ bs2, const float* __restrict__ bh2,
    const float* __restrict__ Wo2,
    ushort* __restrict__ Wt2hi, ushort* __restrict__ Wt2lo,
    ushort* __restrict__ h1hi, ushort* __restrict__ h1lo,
    float* __restrict__ s2, float* __restrict__ hp2)
{
    const int x = blockIdx.x, tid = threadIdx.x;
    if (x >= 128) {                        // ---- rider: Wo2[2+c][n] -> Wt2[n][c] hi/lo
        int t = (x - 128) * 512 + tid;     // 0..65535
        int n = t >> 8, c = t & 255;
        float v = Wo2[(size_t)(2 + c) * 256 + n];
        ushort hi = f2bf(v);
        Wt2hi[n * 256 + c] = hi;
        Wt2lo[n * 256 + c] = f2bf(v - bf2f(hi));
        return;
    }
    __shared__ float sh5[256 * 5];                 // graph s/h (stride 5)
    __shared__ float aggL[64 * 2];                 // this block's 64 agg rows
    __shared__ ushort Ahi[64 * 64], Alo[64 * 64];  // X tile, swizzled
    __shared__ float BCT[64 * CTS];                // union: Bhi/Blo then CT
    __shared__ float part[64 * 8 * 5];
    ushort* Bhi = (ushort*)BCT;
    ushort* Blo = Bhi + 256 * 64;
    float*  CT  = BCT;

    const int lane = tid & 63, wid = tid >> 6;
    const int g = x >> 2, m0 = x * 64, lr0 = (x & 3) * 64;

    // sh1: project all 256 nodes of graph g (redundant x4 across sibling blocks)
    if (tid < 256) {
        const float* xr = X + ((size_t)g * GN + tid) * 64;
        float a0 = 0.f, a1 = 0.f, a2 = 0.f, a3 = 0.f, a4 = 0.f;
#pragma unroll 4
        for (int c0 = 0; c0 < 64; c0 += 4) {
            float4 v = *reinterpret_cast<const float4*>(&xr[c0]);
            float xv[4] = {v.x, v.y, v.z, v.w};
#pragma unroll
            for (int j = 0; j < 4; ++j) {
                int c = c0 + j;
                a0 = fmaf(xv[j], Ws1[c * 3 + 0], a0);
                a1 = fmaf(xv[j], Ws1[c * 3 + 1], a1);
                a2 = fmaf(xv[j], Ws1[c * 3 + 2], a2);
                a3 = fmaf(xv[j], Wh1[c * 2 + 0], a3);
                a4 = fmaf(xv[j], Wh1[c * 2 + 1], a4);
            }
        }
        sh5[tid * 5 + 0] = a0 + bs1[0];
        sh5[tid * 5 + 1] = a1 + bs1[1];
        sh5[tid * 5 + 2] = a2 + bs1[2];
        sh5[tid * 5 + 3] = a3 + bh1[0];
        sh5[tid * 5 + 4] = a4 + bh1[1];
    }
    // A-split: X rows m0..m0+63 -> Ahi/Alo (XOR-swizzled)
#pragma unroll
    for (int i = 0; i < 2; ++i) {
        int lin = tid + i * 512;
        int row = lin >> 4, c4 = (lin & 15) * 4;
        float4 v = *reinterpret_cast<const float4*>(&X[(size_t)(m0 + row) * 64 + c4]);
        int idx = (row * 64 + c4) ^ ((row & 7) << 3);
        ushort4 hi, lo;
        hi.x = f2bf(v.x); lo.x = f2bf(v.x - bf2f(hi.x));
        hi.y = f2bf(v.y); lo.y = f2bf(v.y - bf2f(hi.y));
        hi.z = f2bf(v.z); lo.z = f2bf(v.z - bf2f(hi.z));
        hi.w = f2bf(v.w); lo.w = f2bf(v.w - bf2f(hi.w));
        *reinterpret_cast<ushort4*>(&Ahi[idx]) = hi;
        *reinterpret_cast<ushort4*>(&Alo[idx]) = lo;
    }
    // B-split: Wo1[2+c][n] -> Bhi/Blo [n][c], swizzled
#pragma unroll 4
    for (int i = 0; i < 32; ++i) {
        int e = i * 512 + tid;
        int c = e >> 8, n = e & 255;
        float v = Wo1[(size_t)(2 + c) * 256 + n];
        int idx = (n * 64 + c) ^ ((n & 7) << 3);
        ushort hi = f2bf(v);
        Bhi[idx] = hi;
        Blo[idx] = f2bf(v - bf2f(hi));
    }
    __syncthreads();

    // knn1 for our 64 rows -> aggL
    knn_rows4(sh5, lr0 + wid * 4,      wid * 4,      lane, aggL);
    knn_rows4(sh5, lr0 + 32 + wid * 4, 32 + wid * 4, lane, aggL);

    // gemm1: BM=64, BN=256, K=64; 8 waves (2m x 4n), each 32x64
    const int wm = wid >> 2, wn = wid & 3;
    f32x4 acc[2][4];
#pragma unroll
    for (int mi = 0; mi < 2; ++mi)
#pragma unroll
        for (int ni = 0; ni < 4; ++ni)
            acc[mi][ni] = (f32x4){0.f, 0.f, 0.f, 0.f};
#pragma unroll
    for (int kof = 0; kof < 64; kof += 32) {
        int kch = kof + (lane >> 4) * 8;
        bf16x8 ah[2], al[2], bh[4], bl[4];
#pragma unroll
        for (int mi = 0; mi < 2; ++mi) {
            int r = wm * 32 + mi * 16 + (lane & 15);
            int idx = (r * 64 + kch) ^ ((r & 7) << 3);
            ah[mi] = ld8(&Ahi[idx]); al[mi] = ld8(&Alo[idx]);
        }
#pragma unroll
        for (int ni = 0; ni < 4; ++ni) {
            int n = wn * 64 + ni * 16 + (lane & 15);
            int idx = (n * 64 + kch) ^ ((n & 7) << 3);
            bh[ni] = ld8(&Bhi[idx]); bl[ni] = ld8(&Blo[idx]);
        }
#pragma unroll
        for (int mi = 0; mi < 2; ++mi)
#pragma unroll
            for (int ni = 0; ni < 4; ++ni) {
                acc[mi][ni] = __builtin_amdgcn_mfma_f32_16x16x32_bf16(ah[mi], bh[ni], acc[mi][ni], 0, 0, 0);
                acc[mi][ni] = __builtin_amdgcn_mfma_f32_16x16x32_bf16(ah[mi], bl[ni], acc[mi][ni], 0, 0, 0);
                acc[mi][ni] = __builtin_amdgcn_mfma_f32_16x16x32_bf16(al[mi], bh[ni], acc[mi][ni], 0, 0, 0);
            }
    }
    __syncthreads();   // B reads done (CT may overwrite); aggL complete

    // epilogue: + agg@Wa + bias, leaky -> CT. C/D map: col=lane&15, row=(lane>>4)*4+r
#pragma unroll
    for (int ni = 0; ni < 4; ++ni) {
        int n = wn * 64 + ni * 16 + (lane & 15);
        float w0 = Wo1[n], w1 = Wo1[256 + n], bz = bo1[n];
#pragma unroll
        for (int mi = 0; mi < 2; ++mi) {
            int mb = wm * 32 + mi * 16 + ((lane >> 4) << 2);
#pragma unroll
            for (int r = 0; r < 4; ++r) {
                int ml = mb + r;
                float v = acc[mi][ni][r] + fmaf(aggL[ml * 2 + 0], w0, fmaf(aggL[ml * 2 + 1], w1, bz));
                CT[ml * CTS + n] = v >= 0.f ? v : 0.01f * v;
            }
        }
    }
    __syncthreads();

    // h1 planes from CT (coalesced packed stores)
    {
        int row = tid >> 3, cb = (tid & 7) * 32;
        size_t m = (size_t)(m0 + row);
#pragma unroll
        for (int j = 0; j < 4; ++j) {
            int c = cb + j * 8;
            ushort hi[8], lo[8];
#pragma unroll
            for (int t = 0; t < 8; ++t) {
                float v = CT[row * CTS + c + t];
                hi[t] = f2bf(v);
                lo[t] = f2bf(v - bf2f(hi[t]));
            }
            uint4 wh = make_uint4(pack2(hi[0], hi[1]), pack2(hi[2], hi[3]),
                                  pack2(hi[4], hi[5]), pack2(hi[6], hi[7]));
            uint4 wl = make_uint4(pack2(lo[0], lo[1]), pack2(lo[2], lo[3]),
                                  pack2(lo[4], lo[5]), pack2(lo[6], lo[7]));
            *reinterpret_cast<uint4*>(&h1hi[m * 256 + c]) = wh;
            *reinterpret_cast<uint4*>(&h1lo[m * 256 + c]) = wl;
        }
    }
    // s2/hp2: full 256-col projections, complete rows (plain stores, no atomics)
    {
        int row = tid & 63, sub = tid >> 6;
        float p0 = 0.f, p1 = 0.f, p2 = 0.f, p3 = 0.f, p4 = 0.f;
#pragma unroll
        for (int i = 0; i < 32; ++i) {
            int c = sub * 32 + i;
            float v = CT[row * CTS + c];
            p0 = fmaf(v, Ws2[c * 3 + 0], p0);
            p1 = fmaf(v, Ws2[c * 3 + 1], p1);
            p2 = fmaf(v, Ws2[c * 3 + 2], p2);
            p3 = fmaf(v, Wh2[c * 2 + 0], p3);
            p4 = fmaf(v, Wh2[c * 2 + 1], p4);
        }
        float* pp = &part[(row * 8 + sub) * 5];
        pp[0] = p0; pp[1] = p1; pp[2] = p2; pp[3] = p3; pp[4] = p4;
    }
    __syncthreads();
    if (tid < 320) {
        int row = tid / 5, o = tid - row * 5;
        float sum = 0.f;
#pragma unroll
        for (int k = 0; k < 8; ++k) sum += part[(row * 8 + k) * 5 + o];
        if (o < 3) s2[(m0 + row) * 3 + o] = bs2[o] + sum;
        else       hp2[(m0 + row) * 2 + (o - 3)] = bh2[o - 3] + sum;
    }
}

// ======== K3: knn2 + gemm2 (K=256, BN=256), BM=32, 256 blocks + h2c + s3/hp3 ========
__global__ __launch_bounds__(512) void k3_fused(
    const float* __restrict__ s2, const float* __restrict__ hp2,
    const ushort* __restrict__ h1hi, const ushort* __restrict__ h1lo,
    const ushort* __restrict__ Wt2hi, const ushort* __restrict__ Wt2lo,
    const float* __restrict__ Wo2, const float* __restrict__ bo2,
    const float* __restrict__ Ws3, const float* __restrict__ Wh3,
    const float* __restrict__ bs3, const float* __restrict__ bh3,
    float* __restrict__ h2c, float* __restrict__ s3, float* __restrict__ hp3)
{
    __shared__ float sh5[256 * 5];        // 5120 B
    __shared__ float aggL[32 * 2];        // 256 B
    __shared__ float CT[32 * CTS];        // 32896 B
    __shared__ float part[32 * 16 * 5];   // 10240 B   (total ~48.5 KB -> 3 blocks/CU)

    const int x = blockIdx.x, tid = threadIdx.x;
    const int lane = tid & 63, wid = tid >> 6;
    const int g = x >> 3, m0 = x * 32, lr0 = (x & 7) * 32;

    if (tid < 256) {
        int node = g * GN + tid;
        sh5[tid * 5 + 0] = s2[node * 3 + 0];
        sh5[tid * 5 + 1] = s2[node * 3 + 1];
        sh5[tid * 5 + 2] = s2[node * 3 + 2];
        sh5[tid * 5 + 3] = hp2[node * 2 + 0];
        sh5[tid * 5 + 4] = hp2[node * 2 + 1];
    }
    __syncthreads();
    knn_rows4(sh5, lr0 + wid * 4, wid * 4, lane, aggL);   // 8 waves x 4 = 32 rows
    __syncthreads();   // aggL complete before epilogue

    // gemm2: BM=32, BN=256, K=256; 8 waves 1m x 8n, each 32x32
    f32x4 acc[2][2];
#pragma unroll
    for (int mi = 0; mi < 2; ++mi)
#pragma unroll
        for (int ni = 0; ni < 2; ++ni)
            acc[mi][ni] = (f32x4){0.f, 0.f, 0.f, 0.f};
#pragma unroll 2
    for (int kof = 0; kof < 256; kof += 32) {
        int kch = kof + (lane >> 4) * 8;
        bf16x8 ah[2], al[2], bh[2], bl[2];
#pragma unroll
        for (int mi = 0; mi < 2; ++mi) {
            size_t off = (size_t)(m0 + mi * 16 + (lane & 15)) * 256 + kch;
            ah[mi] = ld8(h1hi + off); al[mi] = ld8(h1lo + off);
        }
#pragma unroll
        for (int ni = 0; ni < 2; ++ni) {
            size_t off = (size_t)(wid * 32 + ni * 16 + (lane & 15)) * 256 + kch;
            bh[ni] = ld8(Wt2hi + off); bl[ni] = ld8(Wt2lo + off);
        }
#pragma unroll
        for (int mi = 0; mi < 2; ++mi)
#pragma unroll
            for (int ni = 0; ni < 2; ++ni) {
                acc[mi][ni] = __builtin_amdgcn_mfma_f32_16x16x32_bf16(ah[mi], bh[ni], acc[mi][ni], 0, 0, 0);
                acc[mi][ni] = __builtin_amdgcn_mfma_f32_16x16x32_bf16(ah[mi], bl[ni], acc[mi][ni], 0, 0, 0);
                acc[mi][ni] = __builtin_amdgcn_mfma_f32_16x16x32_bf16(al[mi], bh[ni], acc[mi][ni], 0, 0, 0);
            }
    }

    // epilogue: + agg@Wa + bias, leaky -> CT. C/D map: col=lane&15, row=(lane>>4)*4+r
#pragma unroll
    for (int ni = 0; ni < 2; ++ni) {
        int n = wid * 32 + ni * 16 + (lane & 15);
        float w0 = Wo2[n], w1 = Wo2[256 + n], bz = bo2[n];
#pragma unroll
        for (int mi = 0; mi < 2; ++mi) {
            int mb = mi * 16 + ((lane >> 4) << 2);
#pragma unroll
            for (int r = 0; r < 4; ++r) {
                int ml = mb + r;   // 0..31
                float v = acc[mi][ni][r] + fmaf(aggL[ml * 2 + 0], w0, fmaf(aggL[ml * 2 + 1], w1, bz));
                CT[ml * CTS + n] = v >= 0.f ? v : 0.01f * v;
            }
        }
    }
    __syncthreads();

    // h2c: block x=8g holds global row g*256 at ml=0
    if ((x & 7) == 0 && tid < 256) h2c[g * 256 + tid] = CT[tid];

    // s3/hp3: full 256-col projections, complete rows (16 subs x 16 cols)
    {
        int row = tid & 31, sub = tid >> 5;
        float p0 = 0.f, p1 = 0.f, p2 = 0.f, p3 = 0.f, p4 = 0.f;
#pragma unroll
        for (int i = 0; i < 16; ++i) {
            int c = sub * 16 + i;
            float v = CT[row * CTS + c];
            p0 = fmaf(v, Ws3[c * 3 + 0], p0);
            p1 = fmaf(v, Ws3[c * 3 + 1], p1);
            p2 = fmaf(v, Ws3[c * 3 + 2], p2);
            p3 = fmaf(v, Wh3[c * 2 + 0], p3);
            p4 = fmaf(v, Wh3[c * 2 + 1], p4);
        }
        float* pp = &part[(row * 16 + sub) * 5];
        pp[0] = p0; pp[1] = p1; pp[2] = p2; pp[3] = p3; pp[4] = p4;
    }
    __syncthreads();
    if (tid < 160) {
        int row = tid / 5, o = tid - row * 5;
        float sum = 0.f;
#pragma unroll
        for (int k = 0; k < 16; ++k) sum += part[(row * 16 + k) * 5 + o];
        if (o < 3) s3[(m0 + row) * 3 + o] = bs3[o] + sum;
        else       hp3[(m0 + row) * 2 + (o - 3)] = bh3[o - 3] + sum;
    }
}

// ================= K4: per-graph kNN of row g*256 + final matvec =================
__global__ __launch_bounds__(256) void knn3_final(
    const float* __restrict__ s, const float* __restrict__ h,
    const float* __restrict__ h2c,
    const float* __restrict__ Wo, const float* __restrict__ bo,
    float* __restrict__ out)
{
    __shared__ float aggL[2];
    __shared__ float pm[8][32];
    int g = blockIdx.x, tid = threadIdx.x;
    if (tid < 64) {
        int lane = tid;
        int base = g * GN, row = g * GN;
        float s0 = s[row * 3 + 0], s1v = s[row * 3 + 1], s2v = s[row * 3 + 2];
        float s2row = s0 * s0 + s1v * s1v + s2v * s2v;
        unsigned key[4]; float2 hs[4];
#pragma unroll
        for (int t = 0; t < 4; ++t) {
            int j = base + lane + 64 * t;
            float xx = s[j * 3 + 0], y = s[j * 3 + 1], z = s[j * 3 + 2];
            float dot = s0 * xx + s1v * y + s2v * z;
            float d2 = s2row + (xx * xx + y * y + z * z) - 2.0f * dot;
            key[t] = __float_as_uint(d2 > 0.f ? d2 : 0.f);
            hs[t] = *reinterpret_cast<const float2*>(&h[(size_t)j * 2]);
        }
        float a0, a1;
        knn_extract(key[0], key[1], key[2], key[3], hs[0], hs[1], hs[2], hs[3], lane, a0, a1);
        if (lane == 63) { aggL[0] = a0; aggL[1] = a1; }
    }
    __syncthreads();
    int o = tid & 31, seg = tid >> 5;
    const float* xr = h2c + g * 256;
    float p = 0.f;
#pragma unroll
    for (int i = 0; i < 32; ++i) {
        int c = seg * 32 + i;
        p = fmaf(xr[c], Wo[(2 + c) * 32 + o], p);
    }
    pm[seg][o] = p;
    __syncthreads();
    if (tid < 32) {
        float acc = fmaf(aggL[0], Wo[o], fmaf(aggL[1], Wo[32 + o], bo[o]));
#pragma unroll
        for (int k = 0; k < 8; ++k) acc += pm[k][o];
        out[g * 32 + o] = acc;
    }
}

extern "C" void kernel_launch(void* const* d_in, const int* in_sizes, int n_in,
                              void* d_out, int out_size, void* d_ws, size_t ws_size,
                              hipStream_t stream) {
    const float* X   = (const float*)d_in[0];
    const float* Ws1 = (const float*)d_in[2];  const float* bs1 = (const float*)d_in[3];
    const float* Wh1 = (const float*)d_in[4];  const float* bh1 = (const float*)d_in[5];
    const float* Wo1 = (const float*)d_in[6];  const float* bo1 = (const float*)d_in[7];
    const float* Ws2 = (const float*)d_in[8];  const float* bs2 = (const float*)d_in[9];
    const float* Wh2 = (const float*)d_in[10]; const float* bh2 = (const float*)d_in[11];
    const float* Wo2 = (const float*)d_in[12]; const float* bo2 = (const float*)d_in[13];
    const float* Ws3 = (const float*)d_in[14]; const float* bs3 = (const float*)d_in[15];
    const float* Wh3 = (const float*)d_in[16]; const float* bh3 = (const float*)d_in[17];
    const float* Wo3 = (const float*)d_in[18]; const float* bo3 = (const float*)d_in[19];

    float* p = (float*)d_ws;
    float* s2   = p; p += NTOT * 3;
    float* hp2  = p; p += NTOT * 2;
    float* s3   = p; p += NTOT * 3;
    float* hp3  = p; p += NTOT * 2;
    float* h2c  = p; p += 32 * 256;
    ushort* q = (ushort*)p;
    ushort* h1hi = q; q += (size_t)NTOT * 256;
    ushort* h1lo = q; q += (size_t)NTOT * 256;
    ushort* Wt2hi = q; q += 256 * 256;
    ushort* Wt2lo = q; q += 256 * 256;

    k2_fused<<<256, 512, 0, stream>>>(X, Ws1, bs1, Wh1, bh1, Wo1, bo1,
                                      Ws2, Wh2, bs2, bh2, Wo2,
                                      Wt2hi, Wt2lo, h1hi, h1lo, s2, hp2);
    k3_fused<<<256, 512, 0, stream>>>(s2, hp2, h1hi, h1lo, Wt2hi, Wt2lo,
                                      Wo2, bo2, Ws3, Wh3, bs3, bh3,
                                      h2c, s3, hp3);
    knn3_final<<<NGRAPH, 256, 0, stream>>>(s3, hp3, h2c, Wo3, bo3, (float*)d_out);
}

// Round 14
// 69.115 us; speedup vs baseline: 4.2168x; 1.3035x over previous
//
#include <hip/hip_runtime.h>
#include <hip/hip_bf16.h>

// GravNet: 32 graphs x 256 nodes, IN=64, HID=256, OUT=32, K=20, SPACE=3, PROP=2
// 3-launch pipeline, zero cross-block sync (handoffs = plain stores across kernel bounds):
//  K2 (384 blk x 512 thr): blocks 0..255: BM=32 — in-block sh1 + kNN own 32 rows +
//     gemm1 (A=X split->LDS swz; B=Wo1 split IN REGISTERS, no LDS, no conflict store)
//     + h1 bf16 planes + complete s2/hp2 rows. LDS ~57KB -> 2 blk/CU.
//     blocks 256..383: rider = Wo2 -> Wt2 hi/lo split.
//     [R14 fix: R13's k2 was 49us — 98KB LDS (1 blk/CU), 128 blocks (half machine),
//      8-way bank-conflict B-split stores (~1M SQ_LDS_BANK_CONFLICT).]
//  K3 (256 blk x 512 thr): BM=32 — knn2 + gemm2 K=256 + h2c + s3/hp3. [R13-verified]
//  K4 (32 blk x 256 thr): per-graph kNN of row g*256 + final matvec.  [R13-verified]
// GEMM x-part: split-bf16 MFMA (hi/lo, 3 products) == fp32 precision.

#define NGRAPH 32
#define GN 256
#define NTOT (NGRAPH*GN) // 8192
#define KNN 20
#define CTS 257          // CT leading dim (floats): 257%32==1 -> conflict-free columns

typedef __attribute__((ext_vector_type(8))) short bf16x8;
typedef __attribute__((ext_vector_type(4))) float f32x4;

__device__ __forceinline__ ushort f2bf(float x) {
    union { float f; unsigned u; } a; a.f = x;
    unsigned r = a.u + 0x7FFFu + ((a.u >> 16) & 1u);   // RNE
    return (ushort)(r >> 16);
}
__device__ __forceinline__ float bf2f(ushort h) {
    union { unsigned u; float f; } b; b.u = ((unsigned)h) << 16;
    return b.f;
}
__device__ __forceinline__ bf16x8 ld8(const ushort* p) {
    return *reinterpret_cast<const bf16x8*>(p);
}
__device__ __forceinline__ unsigned pack2(ushort a, ushort b) {
    return (unsigned)a | ((unsigned)b << 16);
}

// ---- DPP primitives (VALU-only) ----
#define DPP_MIN(v, ctrl, rmask) { \
    unsigned _t = (unsigned)__builtin_amdgcn_update_dpp((int)(v), (int)(v), ctrl, rmask, 0xf, false); \
    (v) = _t < (v) ? _t : (v); }
#define DPP_ADD(v, ctrl, rmask) { \
    float _t = __int_as_float(__builtin_amdgcn_update_dpp(0, __float_as_int(v), ctrl, rmask, 0xf, true)); \
    (v) += _t; }
__device__ __forceinline__ unsigned wave_min_u32(unsigned v) {
    DPP_MIN(v, 0x111, 0xf)
    DPP_MIN(v, 0x112, 0xf)
    DPP_MIN(v, 0x114, 0xf)
    DPP_MIN(v, 0x118, 0xf)
    DPP_MIN(v, 0x142, 0xa)
    DPP_MIN(v, 0x143, 0xc)
    return (unsigned)__builtin_amdgcn_readlane((int)v, 63);
}
__device__ __forceinline__ float wave_sum_f32(float v) {
    DPP_ADD(v, 0x111, 0xf)
    DPP_ADD(v, 0x112, 0xf)
    DPP_ADD(v, 0x114, 0xf)
    DPP_ADD(v, 0x118, 0xf)
    DPP_ADD(v, 0x142, 0xa)
    DPP_ADD(v, 0x143, 0xc)
    return __int_as_float(__builtin_amdgcn_readlane(__float_as_int(v), 63));
}

// ---- serial kNN extraction (K4 only) ----
__device__ __forceinline__ void knn_extract(
    unsigned ua, unsigned ub, unsigned uc, unsigned ud,
    float2 hA, float2 hB, float2 hC, float2 hD,
    int lane, float& out0, float& out1)
{
    float acc0 = 0.f, acc1 = 0.f;
#pragma unroll 1
    for (int it = 0; it < KNN; ++it) {
        unsigned m1 = ua < ub ? ua : ub;
        unsigned m2 = uc < ud ? uc : ud;
        unsigned bv = m1 < m2 ? m1 : m2;
        unsigned gv = wave_min_u32(bv);
        float d2 = __uint_as_float(gv);
        float w = __expf(-10.0f * d2);
        unsigned long long mask = __ballot(bv == gv);
        int wl = __ffsll(mask) - 1;
        if (lane == wl) {
            float h0, h1;
            if (ua == gv)      { h0 = hA.x; h1 = hA.y; ua = 0xFFFFFFFFu; }
            else if (ub == gv) { h0 = hB.x; h1 = hB.y; ub = 0xFFFFFFFFu; }
            else if (uc == gv) { h0 = hC.x; h1 = hC.y; uc = 0xFFFFFFFFu; }
            else               { h0 = hD.x; h1 = hD.y; ud = 0xFFFFFFFFu; }
            acc0 = fmaf(w, h0, acc0);
            acc1 = fmaf(w, h1, acc1);
        }
    }
    out0 = wave_sum_f32(acc0);
    out1 = wave_sum_f32(acc1);
}

// ---- 4 kNN rows per wave (ILP-interleaved chains); sh5 = [256][5] LDS; out -> aggL LDS --
__device__ __forceinline__ void knn_rows4(
    const float* sh5, int srow, int orow, int lane, float* __restrict__ aggL)
{
    float sjx[4], sjy[4], sjz[4], s2j[4];
    float2 hs[4];
#pragma unroll
    for (int t = 0; t < 4; ++t) {
        int j = lane + 64 * t;
        float x = sh5[j * 5 + 0], y = sh5[j * 5 + 1], z = sh5[j * 5 + 2];
        sjx[t] = x; sjy[t] = y; sjz[t] = z;
        s2j[t] = x * x + y * y + z * z;
        hs[t] = make_float2(sh5[j * 5 + 3], sh5[j * 5 + 4]);
    }
    unsigned key[4][4];
    float acc0[4], acc1[4];
#pragma unroll
    for (int r = 0; r < 4; ++r) {
        int rl = srow + r;
        float s0 = sh5[rl * 5 + 0], s1v = sh5[rl * 5 + 1], s2v = sh5[rl * 5 + 2];
        float s2row = s0 * s0 + s1v * s1v + s2v * s2v;
#pragma unroll
        for (int t = 0; t < 4; ++t) {
            float dot = s0 * sjx[t] + s1v * sjy[t] + s2v * sjz[t];
            float d2 = s2row + s2j[t] - 2.0f * dot;
            key[r][t] = __float_as_uint(d2 > 0.f ? d2 : 0.f);
        }
        acc0[r] = 0.f; acc1[r] = 0.f;
    }
#pragma unroll 1
    for (int it = 0; it < KNN; ++it) {
        unsigned bv[4], gv[4];
#pragma unroll
        for (int r = 0; r < 4; ++r) {
            unsigned m1 = key[r][0] < key[r][1] ? key[r][0] : key[r][1];
            unsigned m2 = key[r][2] < key[r][3] ? key[r][2] : key[r][3];
            bv[r] = m1 < m2 ? m1 : m2;
            gv[r] = bv[r];
        }
#define KSTAGE(ctrl, rmask) { \
        DPP_MIN(gv[0], ctrl, rmask) DPP_MIN(gv[1], ctrl, rmask) \
        DPP_MIN(gv[2], ctrl, rmask) DPP_MIN(gv[3], ctrl, rmask) }
        KSTAGE(0x111, 0xf) KSTAGE(0x112, 0xf) KSTAGE(0x114, 0xf)
        KSTAGE(0x118, 0xf) KSTAGE(0x142, 0xa) KSTAGE(0x143, 0xc)
#undef KSTAGE
#pragma unroll
        for (int r = 0; r < 4; ++r) {
            unsigned g = (unsigned)__builtin_amdgcn_readlane((int)gv[r], 63);
            float w = __expf(-10.0f * __uint_as_float(g));
            unsigned long long mask = __ballot(bv[r] == g);
            int wl = __ffsll(mask) - 1;
            if (lane == wl) {
                float h0, h1;
                if (key[r][0] == g)      { h0 = hs[0].x; h1 = hs[0].y; key[r][0] = 0xFFFFFFFFu; }
                else if (key[r][1] == g) { h0 = hs[1].x; h1 = hs[1].y; key[r][1] = 0xFFFFFFFFu; }
                else if (key[r][2] == g) { h0 = hs[2].x; h1 = hs[2].y; key[r][2] = 0xFFFFFFFFu; }
                else                     { h0 = hs[3].x; h1 = hs[3].y; key[r][3] = 0xFFFFFFFFu; }
                acc0[r] = fmaf(w, h0, acc0[r]);
                acc1[r] = fmaf(w, h1, acc1[r]);
            }
        }
    }
#define SSTAGE(ctrl, rmask) { \
    DPP_ADD(acc0[0], ctrl, rmask) DPP_ADD(acc1[0], ctrl, rmask) \
    DPP_ADD(acc0[1], ctrl, rmask) DPP_ADD(acc1[1], ctrl, rmask) \
    DPP_ADD(acc0[2], ctrl, rmask) DPP_ADD(acc1[2], ctrl, rmask) \
    DPP_ADD(acc0[3], ctrl, rmask) DPP_ADD(acc1[3], ctrl, rmask) }
    SSTAGE(0x111, 0xf) SSTAGE(0x112, 0xf) SSTAGE(0x114, 0xf)
    SSTAGE(0x118, 0xf) SSTAGE(0x142, 0xa) SSTAGE(0x143, 0xc)
#undef SSTAGE
    if (lane == 63) {
#pragma unroll
        for (int r = 0; r < 4; ++r) {
            aggL[(orow + r) * 2 + 0] = acc0[r];
            aggL[(orow + r) * 2 + 1] = acc1[r];
        }
    }
}

// ========== K2: BM=32 — sh1 + knn1 + gemm1 (B in regs) + h1 + s2/hp2 | Wt2 rider ==========
__global__ __launch_bounds__(512) void k2_fused(
    const float* __restrict__ X,
    const float* __restrict__ Ws1, const float* __restrict__ bs1,
    const float* __restrict__ Wh1, const float* __restrict__ bh1,
    const float* __restrict__ Wo1, const float* __restrict__ bo1,
    const float* __restrict__ Ws2, const float* __restrict__ Wh2,
    const float* __restrict__ bs2, const float* __restrict__ bh2,
    const float* __restrict__ Wo2,
    ushort* __restrict__ Wt2hi, ushort* __restrict__ Wt2lo,
    ushort* __restrict__ h1hi, ushort* __restrict__ h1lo,
    float* __restrict__ s2, float* __restrict__ hp2)
{
    const int x = blockIdx.x, tid = threadIdx.x;
    if (x >= 256) {                        // ---- rider: Wo2[2+c][n] -> Wt2[n][c] hi/lo
        int t = (x - 256) * 512 + tid;     // 0..65535
        int n = t >> 8, c = t & 255;
        float v = Wo2[(size_t)(2 + c) * 256 + n];
        ushort hi = f2bf(v);
        Wt2hi[n * 256 + c] = hi;
        Wt2lo[n * 256 + c] = f2bf(v - bf2f(hi));
        return;
    }
    __shared__ float sh5[256 * 5];            // 5120 B
    __shared__ float aggL[32 * 2];            // 256 B
    __shared__ ushort Ahi[32 * 64];           // 4096 B (X tile, swizzled)
    __shared__ ushort Alo[32 * 64];           // 4096 B
    __shared__ float CT[32 * CTS];            // 32896 B
    __shared__ float part[32 * 16 * 5];       // 10240 B  -> total ~56.7 KB, 2 blk/CU

    const int lane = tid & 63, wid = tid >> 6;
    const int g = x >> 3, m0 = x * 32, lr0 = (x & 7) * 32;

    // B fragments (Wo1) straight to REGISTERS: wave owns n-range wid*32..+31.
    // Lane-coalesced loads (16 consecutive n per 16-lane group); split in-register.
    bf16x8 bh[2][2], bl[2][2];   // [kof/32][ni]
    {
        int nb = wid * 32 + (lane & 15);
        int k0 = (lane >> 4) * 8;
#pragma unroll
        for (int kk = 0; kk < 2; ++kk)
#pragma unroll
            for (int ni = 0; ni < 2; ++ni) {
                union { bf16x8 v; ushort u[8]; } H, L;
#pragma unroll
                for (int j = 0; j < 8; ++j) {
                    float v = Wo1[(size_t)(2 + kk * 32 + k0 + j) * 256 + nb + ni * 16];
                    ushort hi = f2bf(v);
                    H.u[j] = hi;
                    L.u[j] = f2bf(v - bf2f(hi));
                }
                bh[kk][ni] = H.v; bl[kk][ni] = L.v;
            }
    }
    // sh1: project all 256 nodes of graph g (redundant x8 across sibling blocks)
    if (tid < 256) {
        const float* xr = X + ((size_t)g * GN + tid) * 64;
        float a0 = 0.f, a1 = 0.f, a2 = 0.f, a3 = 0.f, a4 = 0.f;
#pragma unroll 4
        for (int c0 = 0; c0 < 64; c0 += 4) {
            float4 v = *reinterpret_cast<const float4*>(&xr[c0]);
            float xv[4] = {v.x, v.y, v.z, v.w};
#pragma unroll
            for (int j = 0; j < 4; ++j) {
                int c = c0 + j;
                a0 = fmaf(xv[j], Ws1[c * 3 + 0], a0);
                a1 = fmaf(xv[j], Ws1[c * 3 + 1], a1);
                a2 = fmaf(xv[j], Ws1[c * 3 + 2], a2);
                a3 = fmaf(xv[j], Wh1[c * 2 + 0], a3);
                a4 = fmaf(xv[j], Wh1[c * 2 + 1], a4);
            }
        }
        sh5[tid * 5 + 0] = a0 + bs1[0];
        sh5[tid * 5 + 1] = a1 + bs1[1];
        sh5[tid * 5 + 2] = a2 + bs1[2];
        sh5[tid * 5 + 3] = a3 + bh1[0];
        sh5[tid * 5 + 4] = a4 + bh1[1];
    }
    // A-split: X rows m0..m0+31 -> Ahi/Alo (XOR-swizzled), 1 float4/thread
    {
        int row = tid >> 4, c4 = (tid & 15) * 4;
        float4 v = *reinterpret_cast<const float4*>(&X[(size_t)(m0 + row) * 64 + c4]);
        int idx = (row * 64 + c4) ^ ((row & 7) << 3);
        ushort4 hi, lo;
        hi.x = f2bf(v.x); lo.x = f2bf(v.x - bf2f(hi.x));
        hi.y = f2bf(v.y); lo.y = f2bf(v.y - bf2f(hi.y));
        hi.z = f2bf(v.z); lo.z = f2bf(v.z - bf2f(hi.z));
        hi.w = f2bf(v.w); lo.w = f2bf(v.w - bf2f(hi.w));
        *reinterpret_cast<ushort4*>(&Ahi[idx]) = hi;
        *reinterpret_cast<ushort4*>(&Alo[idx]) = lo;
    }
    __syncthreads();

    // knn1: 8 waves x 4 rows = our 32 rows -> aggL
    knn_rows4(sh5, lr0 + wid * 4, wid * 4, lane, aggL);

    // gemm1: BM=32, BN=256 (wave-local 32), K=64; acc[2][2]
    f32x4 acc[2][2];
#pragma unroll
    for (int mi = 0; mi < 2; ++mi)
#pragma unroll
        for (int ni = 0; ni < 2; ++ni)
            acc[mi][ni] = (f32x4){0.f, 0.f, 0.f, 0.f};
#pragma unroll
    for (int kk = 0; kk < 2; ++kk) {
        int kch = kk * 32 + (lane >> 4) * 8;
        bf16x8 ah[2], al[2];
#pragma unroll
        for (int mi = 0; mi < 2; ++mi) {
            int r = mi * 16 + (lane & 15);
            int idx = (r * 64 + kch) ^ ((r & 7) << 3);
            ah[mi] = ld8(&Ahi[idx]); al[mi] = ld8(&Alo[idx]);
        }
#pragma unroll
        for (int mi = 0; mi < 2; ++mi)
#pragma unroll
            for (int ni = 0; ni < 2; ++ni) {
                acc[mi][ni] = __builtin_amdgcn_mfma_f32_16x16x32_bf16(ah[mi], bh[kk][ni], acc[mi][ni], 0, 0, 0);
                acc[mi][ni] = __builtin_amdgcn_mfma_f32_16x16x32_bf16(ah[mi], bl[kk][ni], acc[mi][ni], 0, 0, 0);
                acc[mi][ni] = __builtin_amdgcn_mfma_f32_16x16x32_bf16(al[mi], bh[kk][ni], acc[mi][ni], 0, 0, 0);
            }
    }
    __syncthreads();   // aggL complete (all waves) before epilogue

    // epilogue: + agg@Wa + bias, leaky -> CT. C/D map: col=lane&15, row=(lane>>4)*4+r
#pragma unroll
    for (int ni = 0; ni < 2; ++ni) {
        int n = wid * 32 + ni * 16 + (lane & 15);
        float w0 = Wo1[n], w1 = Wo1[256 + n], bz = bo1[n];
#pragma unroll
        for (int mi = 0; mi < 2; ++mi) {
            int mb = mi * 16 + ((lane >> 4) << 2);
#pragma unroll
            for (int r = 0; r < 4; ++r) {
                int ml = mb + r;   // 0..31
                float v = acc[mi][ni][r] + fmaf(aggL[ml * 2 + 0], w0, fmaf(aggL[ml * 2 + 1], w1, bz));
                CT[ml * CTS + n] = v >= 0.f ? v : 0.01f * v;
            }
        }
    }
    __syncthreads();

    // h1 planes from CT (coalesced packed stores): 512 thr x 16 cols
    {
        int row = tid >> 4, cb = (tid & 15) * 16;
        size_t m = (size_t)(m0 + row);
#pragma unroll
        for (int j = 0; j < 2; ++j) {
            int c = cb + j * 8;
            ushort hi[8], lo[8];
#pragma unroll
            for (int t = 0; t < 8; ++t) {
                float v = CT[row * CTS + c + t];
                hi[t] = f2bf(v);
                lo[t] = f2bf(v - bf2f(hi[t]));
            }
            uint4 wh = make_uint4(pack2(hi[0], hi[1]), pack2(hi[2], hi[3]),
                                  pack2(hi[4], hi[5]), pack2(hi[6], hi[7]));
            uint4 wl = make_uint4(pack2(lo[0], lo[1]), pack2(lo[2], lo[3]),
                                  pack2(lo[4], lo[5]), pack2(lo[6], lo[7]));
            *reinterpret_cast<uint4*>(&h1hi[m * 256 + c]) = wh;
            *reinterpret_cast<uint4*>(&h1lo[m * 256 + c]) = wl;
        }
    }
    // s2/hp2: full 256-col projections, complete rows (16 subs x 16 cols)
    {
        int row = tid & 31, sub = tid >> 5;
        float p0 = 0.f, p1 = 0.f, p2 = 0.f, p3 = 0.f, p4 = 0.f;
#pragma unroll
        for (int i = 0; i < 16; ++i) {
            int c = sub * 16 + i;
            float v = CT[row * CTS + c];
            p0 = fmaf(v, Ws2[c * 3 + 0], p0);
            p1 = fmaf(v, Ws2[c * 3 + 1], p1);
            p2 = fmaf(v, Ws2[c * 3 + 2], p2);
            p3 = fmaf(v, Wh2[c * 2 + 0], p3);
            p4 = fmaf(v, Wh2[c * 2 + 1], p4);
        }
        float* pp = &part[(row * 16 + sub) * 5];
        pp[0] = p0; pp[1] = p1; pp[2] = p2; pp[3] = p3; pp[4] = p4;
    }
    __syncthreads();
    if (tid < 160) {
        int row = tid / 5, o = tid - row * 5;
        float sum = 0.f;
#pragma unroll
        for (int k = 0; k < 16; ++k) sum += part[(row * 16 + k) * 5 + o];
        if (o < 3) s2[(m0 + row) * 3 + o] = bs2[o] + sum;
        else       hp2[(m0 + row) * 2 + (o - 3)] = bh2[o - 3] + sum;
    }
}

// ======== K3: knn2 + gemm2 (K=256, BN=256), BM=32, 256 blocks + h2c + s3/hp3 ========
__global__ __launch_bounds__(512) void k3_fused(
    const float* __restrict__ s2, const float* __restrict__ hp2,
    const ushort* __restrict__ h1hi, const ushort* __restrict__ h1lo,
    const ushort* __restrict__ Wt2hi, const ushort* __restrict__ Wt2lo,
    const float* __restrict__ Wo2, const float* __restrict__ bo2,
    const float* __restrict__ Ws3, const float* __restrict__ Wh3,
    const float* __restrict__ bs3, const float* __restrict__ bh3,
    float* __restrict__ h2c, float* __restrict__ s3, float* __restrict__ hp3)
{
    __shared__ float sh5[256 * 5];
    __shared__ float aggL[32 * 2];
    __shared__ float CT[32 * CTS];
    __shared__ float part[32 * 16 * 5];

    const int x = blockIdx.x, tid = threadIdx.x;
    const int lane = tid & 63, wid = tid >> 6;
    const int g = x >> 3, m0 = x * 32, lr0 = (x & 7) * 32;

    if (tid < 256) {
        int node = g * GN + tid;
        sh5[tid * 5 + 0] = s2[node * 3 + 0];
        sh5[tid * 5 + 1] = s2[node * 3 + 1];
        sh5[tid * 5 + 2] = s2[node * 3 + 2];
        sh5[tid * 5 + 3] = hp2[node * 2 + 0];
        sh5[tid * 5 + 4] = hp2[node * 2 + 1];
    }
    __syncthreads();
    knn_rows4(sh5, lr0 + wid * 4, wid * 4, lane, aggL);   // 8 waves x 4 = 32 rows
    __syncthreads();   // aggL complete before epilogue

    // gemm2: BM=32, BN=256, K=256; 8 waves 1m x 8n, each 32x32
    f32x4 acc[2][2];
#pragma unroll
    for (int mi = 0; mi < 2; ++mi)
#pragma unroll
        for (int ni = 0; ni < 2; ++ni)
            acc[mi][ni] = (f32x4){0.f, 0.f, 0.f, 0.f};
#pragma unroll 2
    for (int kof = 0; kof < 256; kof += 32) {
        int kch = kof + (lane >> 4) * 8;
        bf16x8 ah[2], al[2], bh[2], bl[2];
#pragma unroll
        for (int mi = 0; mi < 2; ++mi) {
            size_t off = (size_t)(m0 + mi * 16 + (lane & 15)) * 256 + kch;
            ah[mi] = ld8(h1hi + off); al[mi] = ld8(h1lo + off);
        }
#pragma unroll
        for (int ni = 0; ni < 2; ++ni) {
            size_t off = (size_t)(wid * 32 + ni * 16 + (lane & 15)) * 256 + kch;
            bh[ni] = ld8(Wt2hi + off); bl[ni] = ld8(Wt2lo + off);
        }
#pragma unroll
        for (int mi = 0; mi < 2; ++mi)
#pragma unroll
            for (int ni = 0; ni < 2; ++ni) {
                acc[mi][ni] = __builtin_amdgcn_mfma_f32_16x16x32_bf16(ah[mi], bh[ni], acc[mi][ni], 0, 0, 0);
                acc[mi][ni] = __builtin_amdgcn_mfma_f32_16x16x32_bf16(ah[mi], bl[ni], acc[mi][ni], 0, 0, 0);
                acc[mi][ni] = __builtin_amdgcn_mfma_f32_16x16x32_bf16(al[mi], bh[ni], acc[mi][ni], 0, 0, 0);
            }
    }

    // epilogue: + agg@Wa + bias, leaky -> CT. C/D map: col=lane&15, row=(lane>>4)*4+r
#pragma unroll
    for (int ni = 0; ni < 2; ++ni) {
        int n = wid * 32 + ni * 16 + (lane & 15);
        float w0 = Wo2[n], w1 = Wo2[256 + n], bz = bo2[n];
#pragma unroll
        for (int mi = 0; mi < 2; ++mi) {
            int mb = mi * 16 + ((lane >> 4) << 2);
#pragma unroll
            for (int r = 0; r < 4; ++r) {
                int ml = mb + r;   // 0..31
                float v = acc[mi][ni][r] + fmaf(aggL[ml * 2 + 0], w0, fmaf(aggL[ml * 2 + 1], w1, bz));
                CT[ml * CTS + n] = v >= 0.f ? v : 0.01f * v;
            }
        }
    }
    __syncthreads();

    // h2c: block x=8g holds global row g*256 at ml=0
    if ((x & 7) == 0 && tid < 256) h2c[g * 256 + tid] = CT[tid];

    // s3/hp3: full 256-col projections, complete rows (16 subs x 16 cols)
    {
        int row = tid & 31, sub = tid >> 5;
        float p0 = 0.f, p1 = 0.f, p2 = 0.f, p3 = 0.f, p4 = 0.f;
#pragma unroll
        for (int i = 0; i < 16; ++i) {
            int c = sub * 16 + i;
            float v = CT[row * CTS + c];
            p0 = fmaf(v, Ws3[c * 3 + 0], p0);
            p1 = fmaf(v, Ws3[c * 3 + 1], p1);
            p2 = fmaf(v, Ws3[c * 3 + 2], p2);
            p3 = fmaf(v, Wh3[c * 2 + 0], p3);
            p4 = fmaf(v, Wh3[c * 2 + 1], p4);
        }
        float* pp = &part[(row * 16 + sub) * 5];
        pp[0] = p0; pp[1] = p1; pp[2] = p2; pp[3] = p3; pp[4] = p4;
    }
    __syncthreads();
    if (tid < 160) {
        int row = tid / 5, o = tid - row * 5;
        float sum = 0.f;
#pragma unroll
        for (int k = 0; k < 16; ++k) sum += part[(row * 16 + k) * 5 + o];
        if (o < 3) s3[(m0 + row) * 3 + o] = bs3[o] + sum;
        else       hp3[(m0 + row) * 2 + (o - 3)] = bh3[o - 3] + sum;
    }
}

// ================= K4: per-graph kNN of row g*256 + final matvec =================
__global__ __launch_bounds__(256) void knn3_final(
    const float* __restrict__ s, const float* __restrict__ h,
    const float* __restrict__ h2c,
    const float* __restrict__ Wo, const float* __restrict__ bo,
    float* __restrict__ out)
{
    __shared__ float aggL[2];
    __shared__ float pm[8][32];
    int g = blockIdx.x, tid = threadIdx.x;
    if (tid < 64) {
        int lane = tid;
        int base = g * GN, row = g * GN;
        float s0 = s[row * 3 + 0], s1v = s[row * 3 + 1], s2v = s[row * 3 + 2];
        float s2row = s0 * s0 + s1v * s1v + s2v * s2v;
        unsigned key[4]; float2 hs[4];
#pragma unroll
        for (int t = 0; t < 4; ++t) {
            int j = base + lane + 64 * t;
            float xx = s[j * 3 + 0], y = s[j * 3 + 1], z = s[j * 3 + 2];
            float dot = s0 * xx + s1v * y + s2v * z;
            float d2 = s2row + (xx * xx + y * y + z * z) - 2.0f * dot;
            key[t] = __float_as_uint(d2 > 0.f ? d2 : 0.f);
            hs[t] = *reinterpret_cast<const float2*>(&h[(size_t)j * 2]);
        }
        float a0, a1;
        knn_extract(key[0], key[1], key[2], key[3], hs[0], hs[1], hs[2], hs[3], lane, a0, a1);
        if (lane == 63) { aggL[0] = a0; aggL[1] = a1; }
    }
    __syncthreads();
    int o = tid & 31, seg = tid >> 5;
    const float* xr = h2c + g * 256;
    float p = 0.f;
#pragma unroll
    for (int i = 0; i < 32; ++i) {
        int c = seg * 32 + i;
        p = fmaf(xr[c], Wo[(2 + c) * 32 + o], p);
    }
    pm[seg][o] = p;
    __syncthreads();
    if (tid < 32) {
        float acc = fmaf(aggL[0], Wo[o], fmaf(aggL[1], Wo[32 + o], bo[o]));
#pragma unroll
        for (int k = 0; k < 8; ++k) acc += pm[k][o];
        out[g * 32 + o] = acc;
    }
}

extern "C" void kernel_launch(void* const* d_in, const int* in_sizes, int n_in,
                              void* d_out, int out_size, void* d_ws, size_t ws_size,
                              hipStream_t stream) {
    const float* X   = (const float*)d_in[0];
    const float* Ws1 = (const float*)d_in[2];  const float* bs1 = (const float*)d_in[3];
    const float* Wh1 = (const float*)d_in[4];  const float* bh1 = (const float*)d_in[5];
    const float* Wo1 = (const float*)d_in[6];  const float* bo1 = (const float*)d_in[7];
    const float* Ws2 = (const float*)d_in[8];  const float* bs2 = (const float*)d_in[9];
    const float* Wh2 = (const float*)d_in[10]; const float* bh2 = (const float*)d_in[11];
    const float* Wo2 = (const float*)d_in[12]; const float* bo2 = (const float*)d_in[13];
    const float* Ws3 = (const float*)d_in[14]; const float* bs3 = (const float*)d_in[15];
    const float* Wh3 = (const float*)d_in[16]; const float* bh3 = (const float*)d_in[17];
    const float* Wo3 = (const float*)d_in[18]; const float* bo3 = (const float*)d_in[19];

    float* p = (float*)d_ws;
    float* s2   = p; p += NTOT * 3;
    float* hp2  = p; p += NTOT * 2;
    float* s3   = p; p += NTOT * 3;
    float* hp3  = p; p += NTOT * 2;
    float* h2c  = p; p += 32 * 256;
    ushort* q = (ushort*)p;
    ushort* h1hi = q; q += (size_t)NTOT * 256;
    ushort* h1lo = q; q += (size_t)NTOT * 256;
    ushort* Wt2hi = q; q += 256 * 256;
    ushort* Wt2lo = q; q += 256 * 256;

    k2_fused<<<384, 512, 0, stream>>>(X, Ws1, bs1, Wh1, bh1, Wo1, bo1,
                                      Ws2, Wh2, bs2, bh2, Wo2,
                                      Wt2hi, Wt2lo, h1hi, h1lo, s2, hp2);
    k3_fused<<<256, 512, 0, stream>>>(s2, hp2, h1hi, h1lo, Wt2hi, Wt2lo,
                                      Wo2, bo2, Ws3, Wh3, bs3, bh3,
                                      h2c, s3, hp3);
    knn3_final<<<NGRAPH, 256, 0, stream>>>(s3, hp3, h2c, Wo3, bo3, (float*)d_out);
}